// Round 1
// baseline (4006.932 us; speedup 1.0000x reference)
//
#include <hip/hip_runtime.h>
#include <hip/hip_bf16.h>
#include <math.h>

// Problem constants
#define BB 8
#define CC 192
#define HH 56
#define WW 56
#define NPTS 3136        // H*W
#define OUTC 192
#define KNN 9
#define NTILES 49        // NPTS/64

// ---------------------------------------------------------------------------
// top-k insertion helpers: sorted ascending by (dist, idx) lexicographic.
// Fully unrolled static indexing so arrays stay in VGPRs (no scratch).
// ---------------------------------------------------------------------------
__device__ __forceinline__ void ins12(float (&d)[12], int (&ix)[12], float nd, int ni) {
    if (!((nd < d[11]) || (nd == d[11] && ni < ix[11]))) return;
    d[11] = nd; ix[11] = ni;
#pragma unroll
    for (int q = 11; q > 0; --q) {
        if ((d[q] < d[q-1]) || (d[q] == d[q-1] && ix[q] < ix[q-1])) {
            float t = d[q]; d[q] = d[q-1]; d[q-1] = t;
            int t2 = ix[q]; ix[q] = ix[q-1]; ix[q-1] = t2;
        }
    }
}

__device__ __forceinline__ void ins9d(double (&d)[9], int (&ix)[9], double nd, int ni) {
    if (!((nd < d[8]) || (nd == d[8] && ni < ix[8]))) return;
    d[8] = nd; ix[8] = ni;
#pragma unroll
    for (int q = 8; q > 0; --q) {
        if ((d[q] < d[q-1]) || (d[q] == d[q-1] && ix[q] < ix[q-1])) {
            double t = d[q]; d[q] = d[q-1]; d[q-1] = t;
            int t2 = ix[q]; ix[q] = ix[q-1]; ix[q-1] = t2;
        }
    }
}

// ---------------------------------------------------------------------------
// K1: transpose (B,C,N)->(B,N,C), L2-normalize rows; emit xn, norm, sq(xn)
// grid (49, 8), block 256
// ---------------------------------------------------------------------------
__global__ __launch_bounds__(256) void k1_normalize(const float* __restrict__ x,
                                                    float* __restrict__ xn,
                                                    float* __restrict__ normv,
                                                    float* __restrict__ sqv) {
    const int b  = blockIdx.y;
    const int n0 = blockIdx.x * 64;
    __shared__ float tile[64 * 193];   // pad 193 to dodge bank conflicts
    __shared__ float red[4][64];
    __shared__ float inv[64];
    const int tid = threadIdx.x;
    const int p   = tid & 63;
    const int cg  = tid >> 6;          // 0..3
    const float* xb = x + (size_t)b * CC * NPTS;

    float acc = 0.f;
#pragma unroll 4
    for (int t = 0; t < 48; ++t) {
        const int c = cg * 48 + t;
        const float v = xb[(size_t)c * NPTS + n0 + p];
        tile[p * 193 + c] = v;
        acc += v * v;
    }
    red[cg][p] = acc;
    __syncthreads();
    if (cg == 0) {
        const float s  = red[0][p] + red[1][p] + red[2][p] + red[3][p];
        float nc = sqrtf(s);
        nc = fmaxf(nc, 1e-12f);
        normv[b * NPTS + n0 + p] = nc;
        const float iv = 1.0f / nc;
        inv[p] = iv;
        sqv[b * NPTS + n0 + p] = s * iv * iv;
    }
    __syncthreads();
    float* dst = xn + ((size_t)b * NPTS + n0) * CC;
    for (int q = tid; q < 64 * CC / 4; q += 256) {
        const int f   = q * 4;
        const int row = f / CC;
        const int c   = f - row * CC;
        const float iv = inv[row];
        float4 v;
        v.x = tile[row * 193 + c + 0] * iv;
        v.y = tile[row * 193 + c + 1] * iv;
        v.z = tile[row * 193 + c + 2] * iv;
        v.w = tile[row * 193 + c + 3] * iv;
        *(float4*)&dst[f] = v;
    }
}

// ---------------------------------------------------------------------------
// K2: fused cosine-distance GEMM + running top-12 + fp64 re-rank -> idx[b,n,9]
// grid (49, 8), block 256.  LDS ~62 KB -> 2 blocks/CU.
// ---------------------------------------------------------------------------
#define CDI(s, p, q) (((s) * 64 + (p)) * 13 + (q))

__global__ __launch_bounds__(256) void k2_knn(const float* __restrict__ xn,
                                              const float* __restrict__ sqv,
                                              int* __restrict__ idxout) {
    const int b  = blockIdx.y;
    const int r0 = blockIdx.x * 64;
    __shared__ __align__(16) float rowf[64 * 36];   // 32-c chunk, pad 36
    __shared__ __align__(16) float colf[64 * 36];
    __shared__ __align__(16) float dtraw[64 * 65];  // dist tile; reused as double[] in refine
    __shared__ float rsq[64];
    __shared__ float csq[64];
    __shared__ float cd[4 * 64 * 13];
    __shared__ int   ci[4 * 64 * 13];

    const int tid = threadIdx.x;
    const int tx  = tid & 15;
    const int ty  = tid >> 4;
    const float* xb = xn + (size_t)b * NPTS * CC;

    float t12d[12]; int t12i[12];
#pragma unroll
    for (int q = 0; q < 12; ++q) { t12d[q] = 3.4e38f; t12i[q] = 0x7fffffff; }

    if (tid < 64) rsq[tid] = sqv[b * NPTS + r0 + tid];

    for (int ct = 0; ct < NTILES; ++ct) {
        const int c0 = ct * 64;
        if (tid < 64) csq[tid] = sqv[b * NPTS + c0 + tid];
        float4 acc[4][4];
#pragma unroll
        for (int i = 0; i < 4; ++i)
#pragma unroll
            for (int j = 0; j < 4; ++j) acc[i][j] = make_float4(0.f, 0.f, 0.f, 0.f);

        for (int ch = 0; ch < 6; ++ch) {
            const int cb = ch * 32;
            __syncthreads();
#pragma unroll
            for (int rep = 0; rep < 2; ++rep) {
                const int q   = tid + rep * 256;   // 0..511
                const int row = q >> 3;
                const int c4  = (q & 7) << 2;
                *(float4*)&rowf[row * 36 + c4] = *(const float4*)&xb[(size_t)(r0 + row) * CC + cb + c4];
                *(float4*)&colf[row * 36 + c4] = *(const float4*)&xb[(size_t)(c0 + row) * CC + cb + c4];
            }
            __syncthreads();
#pragma unroll
            for (int ccc = 0; ccc < 32; ccc += 4) {
                float4 av[4], bv[4];
#pragma unroll
                for (int i = 0; i < 4; ++i) av[i] = *(const float4*)&rowf[(i * 16 + ty) * 36 + ccc];
#pragma unroll
                for (int j = 0; j < 4; ++j) bv[j] = *(const float4*)&colf[(j * 16 + tx) * 36 + ccc];
#pragma unroll
                for (int i = 0; i < 4; ++i)
#pragma unroll
                    for (int j = 0; j < 4; ++j) {
                        acc[i][j].x += av[i].x * bv[j].x;
                        acc[i][j].y += av[i].y * bv[j].y;
                        acc[i][j].z += av[i].z * bv[j].z;
                        acc[i][j].w += av[i].w * bv[j].w;
                    }
            }
        }
        // distances into LDS tile
#pragma unroll
        for (int i = 0; i < 4; ++i)
#pragma unroll
            for (int j = 0; j < 4; ++j) {
                const float4 a4 = acc[i][j];
                const float dot = (a4.x + a4.y) + (a4.z + a4.w);
                dtraw[(i * 16 + ty) * 65 + (j * 16 + tx)] =
                    rsq[i * 16 + ty] + csq[j * 16 + tx] - 2.0f * dot;
            }
        __syncthreads();
        // scan: thread = (row p, col-segment s of 16)
        {
            const int p = tid & 63;
            const int s = tid >> 6;
#pragma unroll
            for (int t = 0; t < 16; ++t) {
                const int ml = s * 16 + t;
                ins12(t12d, t12i, dtraw[p * 65 + ml], c0 + ml);
            }
        }
        // next iteration's first __syncthreads orders scan before LDS overwrite
    }

    // dump per-thread lists
    {
        const int p = tid & 63;
        const int s = tid >> 6;
#pragma unroll
        for (int q = 0; q < 12; ++q) {
            cd[CDI(s, p, q)] = t12d[q];
            ci[CDI(s, p, q)] = t12i[q];
        }
    }
    __syncthreads();
    // merge 4 lists per row -> top-12; store indices into own s=0 slot of ci
    if (tid < 64) {
        float fd[12]; int fi[12];
#pragma unroll
        for (int q = 0; q < 12; ++q) { fd[q] = 3.4e38f; fi[q] = 0x7fffffff; }
        for (int s = 0; s < 4; ++s)
#pragma unroll
            for (int q = 0; q < 12; ++q)
                ins12(fd, fi, cd[CDI(s, tid, q)], ci[CDI(s, tid, q)]);
#pragma unroll
        for (int q = 0; q < 12; ++q) ci[CDI(0, tid, q)] = fi[q];
    }
    __syncthreads();
    // fp64 re-rank of the 12 candidates (4 threads/row x 3 cands)
    double* dd = reinterpret_cast<double*>(dtraw);
    {
        const int p = tid >> 2;
        const int s = tid & 3;
        const float* xr = xb + (size_t)(r0 + p) * CC;
#pragma unroll
        for (int t = 0; t < 3; ++t) {
            const int cs = s + t * 4;
            const int m  = ci[CDI(0, p, cs)];
            const float* xm = xb + (size_t)m * CC;
            double dot = 0.0, sqm = 0.0, sqn = 0.0;
            for (int c = 0; c < CC; ++c) {
                const double a  = (double)xr[c];
                const double b2 = (double)xm[c];
                dot += a * b2;
                sqm += b2 * b2;
                sqn += a * a;
            }
            dd[p * 13 + cs] = sqn + sqm - 2.0 * dot;
        }
    }
    __syncthreads();
    if (tid < 64) {
        double fd[9]; int fi[9];
#pragma unroll
        for (int q = 0; q < 9; ++q) { fd[q] = 1e300; fi[q] = 0x7fffffff; }
#pragma unroll
        for (int cs = 0; cs < 12; ++cs)
            ins9d(fd, fi, dd[tid * 13 + cs], ci[CDI(0, tid, cs)]);
#pragma unroll
        for (int q = 0; q < 9; ++q)
            idxout[((size_t)b * NPTS + r0 + tid) * KNN + q] = fi[q];
    }
}

// ---------------------------------------------------------------------------
// K3a: Wcat[0:192][c]   = W1 - W2   (u weights)
//      Wcat[192:384][c] = W2        (v weights)
// ---------------------------------------------------------------------------
__global__ __launch_bounds__(256) void k3a_wcat(const float* __restrict__ cw,
                                                float* __restrict__ Wcat) {
    const int i = blockIdx.x * 256 + threadIdx.x;
    if (i < OUTC * CC) {
        const int o = i / CC, c = i - o * CC;
        const float w1 = cw[o * (2 * CC) + c];
        const float w2 = cw[o * (2 * CC) + CC + c];
        Wcat[o * CC + c]          = w1 - w2;
        Wcat[(OUTC + o) * CC + c] = w2;
    }
}

// ---------------------------------------------------------------------------
// K3b: uv[m][0:192] = norm[m]*(xn[m]·(W1-W2)^T) + conv_b ; uv[m][192:384] = norm[m]*(xn[m]·W2^T)
// grid (392, 6), block 256, 64x64 tiles, k-chunks of 16
// ---------------------------------------------------------------------------
__global__ __launch_bounds__(256) void k3_gemm(const float* __restrict__ xn,
                                               const float* __restrict__ Wcat,
                                               const float* __restrict__ normv,
                                               const float* __restrict__ conv_b,
                                               float* __restrict__ uv) {
    const int m0 = blockIdx.x * 64;
    const int o0 = blockIdx.y * 64;
    __shared__ __align__(16) float As[64 * 20];
    __shared__ __align__(16) float Bs[64 * 20];
    const int tid = threadIdx.x;
    const int tx  = tid & 15;
    const int ty  = tid >> 4;
    float acc[4][4] = {};

    for (int k0 = 0; k0 < CC; k0 += 16) {
        __syncthreads();
        const int row = tid >> 2;
        const int k4  = (tid & 3) << 2;
        *(float4*)&As[row * 20 + k4] = *(const float4*)&xn[(size_t)(m0 + row) * CC + k0 + k4];
        *(float4*)&Bs[row * 20 + k4] = *(const float4*)&Wcat[(size_t)(o0 + row) * CC + k0 + k4];
        __syncthreads();
#pragma unroll
        for (int kk = 0; kk < 16; kk += 4) {
            float4 av[4], bv[4];
#pragma unroll
            for (int i = 0; i < 4; ++i) av[i] = *(const float4*)&As[(i * 16 + ty) * 20 + kk];
#pragma unroll
            for (int j = 0; j < 4; ++j) bv[j] = *(const float4*)&Bs[(j * 16 + tx) * 20 + kk];
#pragma unroll
            for (int i = 0; i < 4; ++i)
#pragma unroll
                for (int j = 0; j < 4; ++j)
                    acc[i][j] += av[i].x * bv[j].x + av[i].y * bv[j].y +
                                 av[i].z * bv[j].z + av[i].w * bv[j].w;
        }
    }
    float nrm[4];
#pragma unroll
    for (int i = 0; i < 4; ++i) nrm[i] = normv[m0 + i * 16 + ty];
#pragma unroll
    for (int i = 0; i < 4; ++i)
#pragma unroll
        for (int j = 0; j < 4; ++j) {
            const int o = o0 + j * 16 + tx;
            float vvv = acc[i][j] * nrm[i];
            if (o < OUTC) vvv += conv_b[o];
            uv[(size_t)(m0 + i * 16 + ty) * (2 * OUTC) + o] = vvv;
        }
}

// ---------------------------------------------------------------------------
// K4a: per-block partial BN sums over y = u + v[idx]
// grid (49, 8), block 192 (thread = channel o)
// ---------------------------------------------------------------------------
__global__ __launch_bounds__(192) void k4_stats(const float* __restrict__ uv,
                                                const int* __restrict__ idxb,
                                                float* __restrict__ partials) {
    const int b  = blockIdx.y;
    const int n0 = blockIdx.x * 64;
    const int o  = threadIdx.x;
    const size_t base = (size_t)b * NPTS;
    float aS = 0.f, aQ = 0.f;
    for (int p = 0; p < 64; ++p) {
        const int n = n0 + p;
        const float u = uv[(base + n) * (2 * OUTC) + o];
        const int* ix = &idxb[(base + n) * KNN];
#pragma unroll
        for (int k = 0; k < KNN; ++k) {
            const int m  = ix[k];
            const float v = uv[(base + m) * (2 * OUTC) + OUTC + o];
            const float y = u + v;
            aS += y;
            aQ += y * y;
        }
    }
    const int blk = blockIdx.y * NTILES + blockIdx.x;
    partials[(size_t)blk * (2 * OUTC) + o]         = aS;
    partials[(size_t)blk * (2 * OUTC) + OUTC + o]  = aQ;
}

// ---------------------------------------------------------------------------
// K4b: reduce partials deterministically -> scale/shift per channel
// grid 1, block 192
// ---------------------------------------------------------------------------
__global__ __launch_bounds__(192) void k4b_finalize(const float* __restrict__ partials,
                                                    const float* __restrict__ gamma,
                                                    const float* __restrict__ beta,
                                                    float* __restrict__ scsh) {
    const int o = threadIdx.x;
    float S = 0.f, Q = 0.f;
    for (int blk = 0; blk < BB * NTILES; ++blk) {
        S += partials[(size_t)blk * (2 * OUTC) + o];
        Q += partials[(size_t)blk * (2 * OUTC) + OUTC + o];
    }
    const float cnt  = (float)BB * (float)NPTS * (float)KNN;
    const float mean = S / cnt;
    float var = Q / cnt - mean * mean;
    var = fmaxf(var, 0.0f);
    const float scale = gamma[o] * rsqrtf(var + 1e-5f);
    scsh[o]        = scale;
    scsh[OUTC + o] = beta[o] - mean * scale;
}

// ---------------------------------------------------------------------------
// K5: out[b][o][n] = max_k gelu((u+v[idx])*scale + shift)
// grid (49, 8), block 256 (thread = point p x o-group of 48)
// ---------------------------------------------------------------------------
__global__ __launch_bounds__(256) void k5_final(const float* __restrict__ uv,
                                                const int* __restrict__ idxb,
                                                const float* __restrict__ scsh,
                                                float* __restrict__ out) {
    const int b  = blockIdx.y;
    const int n0 = blockIdx.x * 64;
    __shared__ float zb[64 * 193];
    __shared__ float ssc[OUTC];
    __shared__ float ssh[OUTC];
    const int tid = threadIdx.x;
    for (int q = tid; q < OUTC; q += 256) {
        ssc[q] = scsh[q];
        ssh[q] = scsh[OUTC + q];
    }
    __syncthreads();
    const int p  = tid >> 2;
    const int og = tid & 3;
    const size_t base = (size_t)b * NPTS;
    const int n = n0 + p;
    float zmax[48];
#pragma unroll
    for (int t = 0; t < 48; ++t) zmax[t] = -3.4e38f;
    const float* ur = &uv[(base + n) * (2 * OUTC) + og * 48];
    const int* ix = &idxb[(base + n) * KNN];
#pragma unroll
    for (int k = 0; k < KNN; ++k) {
        const int m = ix[k];
        const float* vrow = &uv[(base + m) * (2 * OUTC) + OUTC + og * 48];
#pragma unroll
        for (int t4 = 0; t4 < 12; ++t4) {
            const float4 uu = *(const float4*)&ur[t4 * 4];
            const float4 vv = *(const float4*)&vrow[t4 * 4];
            const int ob = og * 48 + t4 * 4;
            float y, z, g;
            y = uu.x + vv.x; z = y * ssc[ob + 0] + ssh[ob + 0];
            g = 0.5f * z * (1.0f + erff(z * 0.70710678118654752f));
            zmax[t4 * 4 + 0] = fmaxf(zmax[t4 * 4 + 0], g);
            y = uu.y + vv.y; z = y * ssc[ob + 1] + ssh[ob + 1];
            g = 0.5f * z * (1.0f + erff(z * 0.70710678118654752f));
            zmax[t4 * 4 + 1] = fmaxf(zmax[t4 * 4 + 1], g);
            y = uu.z + vv.z; z = y * ssc[ob + 2] + ssh[ob + 2];
            g = 0.5f * z * (1.0f + erff(z * 0.70710678118654752f));
            zmax[t4 * 4 + 2] = fmaxf(zmax[t4 * 4 + 2], g);
            y = uu.w + vv.w; z = y * ssc[ob + 3] + ssh[ob + 3];
            g = 0.5f * z * (1.0f + erff(z * 0.70710678118654752f));
            zmax[t4 * 4 + 3] = fmaxf(zmax[t4 * 4 + 3], g);
        }
    }
#pragma unroll
    for (int t = 0; t < 48; ++t) zb[p * 193 + og * 48 + t] = zmax[t];
    __syncthreads();
    float* ob2 = out + (size_t)b * OUTC * NPTS;
    for (int q = tid; q < 64 * OUTC; q += 256) {
        const int o  = q >> 6;
        const int pp = q & 63;
        ob2[(size_t)o * NPTS + n0 + pp] = zb[pp * 193 + o];
    }
}

// ---------------------------------------------------------------------------
extern "C" void kernel_launch(void* const* d_in, const int* in_sizes, int n_in,
                              void* d_out, int out_size, void* d_ws, size_t ws_size,
                              hipStream_t stream) {
    const float* x        = (const float*)d_in[0];
    const float* conv_w   = (const float*)d_in[1];
    const float* conv_b   = (const float*)d_in[2];
    const float* bn_gamma = (const float*)d_in[3];
    const float* bn_beta  = (const float*)d_in[4];
    float* out = (float*)d_out;

    // workspace layout (floats)
    float* ws = (float*)d_ws;
    const size_t SZ_XN   = (size_t)BB * NPTS * CC;        // 4,816,896
    const size_t SZ_NV   = (size_t)BB * NPTS;             // 25,088
    float* xn       = ws;
    float* normv    = xn + SZ_XN;
    float* sqv      = normv + SZ_NV;
    int*   idxb     = (int*)(sqv + SZ_NV);                // B*N*K ints
    float* Wcat     = (float*)(idxb + (size_t)BB * NPTS * KNN);
    float* uv       = Wcat + (size_t)(2 * OUTC) * CC;
    float* partials = uv + (size_t)BB * NPTS * (2 * OUTC);
    float* scsh     = partials + (size_t)BB * NTILES * (2 * OUTC);

    k1_normalize<<<dim3(NTILES, BB), 256, 0, stream>>>(x, xn, normv, sqv);
    k2_knn<<<dim3(NTILES, BB), 256, 0, stream>>>(xn, sqv, idxb);
    k3a_wcat<<<(OUTC * CC + 255) / 256, 256, 0, stream>>>(conv_w, Wcat);
    k3_gemm<<<dim3(BB * NPTS / 64, (2 * OUTC) / 64), 256, 0, stream>>>(xn, Wcat, normv, conv_b, uv);
    k4_stats<<<dim3(NTILES, BB), 192, 0, stream>>>(uv, idxb, partials);
    k4b_finalize<<<1, 192, 0, stream>>>(partials, bn_gamma, bn_beta, scsh);
    k5_final<<<dim3(NTILES, BB), 256, 0, stream>>>(uv, idxb, scsh, out);
}

// Round 2
// 3280.586 us; speedup vs baseline: 1.2214x; 1.2214x over previous
//
#include <hip/hip_runtime.h>
#include <hip/hip_bf16.h>
#include <math.h>

// Problem constants
#define BB 8
#define CC 192
#define HH 56
#define WW 56
#define NPTS 3136        // H*W
#define OUTC 192
#define KNN 9
#define NTILES 49        // NPTS/64

typedef __bf16 bf16x8 __attribute__((ext_vector_type(8)));
typedef float  f32x16 __attribute__((ext_vector_type(16)));

__device__ __forceinline__ unsigned short f2bf(float f) {
    unsigned u = __float_as_uint(f);
    u += 0x7fffu + ((u >> 16) & 1u);       // RNE
    return (unsigned short)(u >> 16);
}
__device__ __forceinline__ float bf2f(unsigned short h) {
    return __uint_as_float(((unsigned)h) << 16);
}

// ---------------------------------------------------------------------------
// top-k insertion helpers: sorted ascending by (dist, idx) lexicographic.
// ---------------------------------------------------------------------------
__device__ __forceinline__ void ins12(float (&d)[12], int (&ix)[12], float nd, int ni) {
    if (!((nd < d[11]) || (nd == d[11] && ni < ix[11]))) return;
    d[11] = nd; ix[11] = ni;
#pragma unroll
    for (int q = 11; q > 0; --q) {
        if ((d[q] < d[q-1]) || (d[q] == d[q-1] && ix[q] < ix[q-1])) {
            float t = d[q]; d[q] = d[q-1]; d[q-1] = t;
            int t2 = ix[q]; ix[q] = ix[q-1]; ix[q-1] = t2;
        }
    }
}

__device__ __forceinline__ void ins9d(double (&d)[9], int (&ix)[9], double nd, int ni) {
    if (!((nd < d[8]) || (nd == d[8] && ni < ix[8]))) return;
    d[8] = nd; ix[8] = ni;
#pragma unroll
    for (int q = 8; q > 0; --q) {
        if ((d[q] < d[q-1]) || (d[q] == d[q-1] && ix[q] < ix[q-1])) {
            double t = d[q]; d[q] = d[q-1]; d[q-1] = t;
            int t2 = ix[q]; ix[q] = ix[q-1]; ix[q-1] = t2;
        }
    }
}

// ---------------------------------------------------------------------------
// K1: transpose (B,C,N)->(B,N,C), L2-normalize rows; emit xn (f32),
//     xh/xl (bf16 hi/lo split of xn), norm, sq(xn)
// grid (49, 8), block 256
// ---------------------------------------------------------------------------
__global__ __launch_bounds__(256) void k1_normalize(const float* __restrict__ x,
                                                    float* __restrict__ xn,
                                                    unsigned short* __restrict__ xh,
                                                    unsigned short* __restrict__ xl,
                                                    float* __restrict__ normv,
                                                    float* __restrict__ sqv) {
    const int b  = blockIdx.y;
    const int n0 = blockIdx.x * 64;
    __shared__ float tile[64 * 193];
    __shared__ float red[4][64];
    __shared__ float inv[64];
    const int tid = threadIdx.x;
    const int p   = tid & 63;
    const int cg  = tid >> 6;
    const float* xb = x + (size_t)b * CC * NPTS;

    float acc = 0.f;
#pragma unroll 4
    for (int t = 0; t < 48; ++t) {
        const int c = cg * 48 + t;
        const float v = xb[(size_t)c * NPTS + n0 + p];
        tile[p * 193 + c] = v;
        acc += v * v;
    }
    red[cg][p] = acc;
    __syncthreads();
    if (cg == 0) {
        const float s  = red[0][p] + red[1][p] + red[2][p] + red[3][p];
        float nc = sqrtf(s);
        nc = fmaxf(nc, 1e-12f);
        normv[b * NPTS + n0 + p] = nc;
        const float iv = 1.0f / nc;
        inv[p] = iv;
        sqv[b * NPTS + n0 + p] = s * iv * iv;
    }
    __syncthreads();
    const size_t base = ((size_t)b * NPTS + n0) * CC;
    float* dst = xn + base;
    for (int q = tid; q < 64 * CC / 4; q += 256) {
        const int f   = q * 4;
        const int row = f / CC;
        const int c   = f - row * CC;
        const float iv = inv[row];
        float4 v;
        v.x = tile[row * 193 + c + 0] * iv;
        v.y = tile[row * 193 + c + 1] * iv;
        v.z = tile[row * 193 + c + 2] * iv;
        v.w = tile[row * 193 + c + 3] * iv;
        *(float4*)&dst[f] = v;
        ushort4 hv, lv;
        hv.x = f2bf(v.x); lv.x = f2bf(v.x - bf2f(hv.x));
        hv.y = f2bf(v.y); lv.y = f2bf(v.y - bf2f(hv.y));
        hv.z = f2bf(v.z); lv.z = f2bf(v.z - bf2f(hv.z));
        hv.w = f2bf(v.w); lv.w = f2bf(v.w - bf2f(hv.w));
        *(ushort4*)&xh[base + f] = hv;
        *(ushort4*)&xl[base + f] = lv;
    }
}

// ---------------------------------------------------------------------------
// K2: MFMA split-bf16 cosine-distance GEMM + running top-12 + fp64 re-rank
// grid (49, 8), block 256 (4 waves; wave w = (row strip w>>1, col strip w&1),
// each wave one 32x32 mfma_f32_32x32x16_bf16 accumulator).
// dot ~= hi.hi + lo.hi + hi.lo  (error ~1e-5; re-rank makes it exact)
// ---------------------------------------------------------------------------
#define CDI(s, p, q) (((s) * 64 + (p)) * 13 + (q))

__global__ __launch_bounds__(256) void k2_knn(const float* __restrict__ xn,
                                              const unsigned short* __restrict__ xh,
                                              const unsigned short* __restrict__ xl,
                                              const float* __restrict__ sqv,
                                              int* __restrict__ idxout) {
    const int b  = blockIdx.y;
    const int r0 = blockIdx.x * 64;

    __shared__ __align__(16) char smem[68352];
    unsigned short* Bh_s = (unsigned short*)smem;            // 64 rows * 200 shorts (400B, bank-balanced)
    unsigned short* Bl_s = (unsigned short*)(smem + 25600);  // 64 * 200
    float* dtile = (float*)(smem + 51200);                   // 64*65 f32 = 16640 B
    float* rsq_s = (float*)(smem + 67840);                   // 64 f32
    float* csq_s = (float*)(smem + 68096);                   // 64 f32
    // aliases used AFTER the main tile loop:
    float*  cd = (float*)smem;                                // 4*64*13 f32
    int*    ci = (int*)(smem + 13312);                        // 4*64*13 i32
    double* dd = (double*)(smem + 51200);                     // 64*13 f64

    const int tid  = threadIdx.x;
    const int w    = tid >> 6;
    const int lane = tid & 63;
    const int wr   = w >> 1, wc = w & 1;
    const int l31  = lane & 31;
    const int lhi  = lane >> 5;
    const int koffe = lhi * 8;              // k element offset within 16-chunk
    const float* xb = xn + (size_t)b * NPTS * CC;

    // --- A fragments in registers: rows r0 + wr*32 + l31, 12 K-chunks, hi+lo
    const size_t abase = ((size_t)b * NPTS + (r0 + wr * 32 + l31)) * CC;
    bf16x8 Ah[12], Al[12];
#pragma unroll
    for (int c = 0; c < 12; ++c) {
        Ah[c] = *(const bf16x8*)(const void*)(xh + abase + c * 16 + koffe);
        Al[c] = *(const bf16x8*)(const void*)(xl + abase + c * 16 + koffe);
    }
    if (tid < 64) rsq_s[tid] = sqv[b * NPTS + r0 + tid];

    float t12d[12]; int t12i[12];
#pragma unroll
    for (int q = 0; q < 12; ++q) { t12d[q] = 3.4e38f; t12i[q] = 0x7fffffff; }

    for (int ct = 0; ct < NTILES; ++ct) {
        const int c0 = ct * 64;
        __syncthreads();   // prev scan / prev B-reads done before restaging
        if (tid < 64) csq_s[tid] = sqv[b * NPTS + c0 + tid];
        // stage 64 col-points (hi+lo), 1536 16B-chunks, 6 per thread per array
#pragma unroll
        for (int rep = 0; rep < 6; ++rep) {
            const int cidx  = rep * 256 + tid;
            const int point = cidx / 24;
            const int c8    = cidx - point * 24;
            const size_t g  = ((size_t)b * NPTS + c0 + point) * CC + c8 * 8;
            *(uint4*)(void*)&Bh_s[point * 200 + c8 * 8] = *(const uint4*)(const void*)(xh + g);
            *(uint4*)(void*)&Bl_s[point * 200 + c8 * 8] = *(const uint4*)(const void*)(xl + g);
        }
        __syncthreads();

        f32x16 acc;
#pragma unroll
        for (int r = 0; r < 16; ++r) acc[r] = 0.f;
        const int bbase = (wc * 32 + l31) * 200 + koffe;
#pragma unroll
        for (int c = 0; c < 12; ++c) {
            const bf16x8 bh = *(const bf16x8*)(const void*)&Bh_s[bbase + c * 16];
            acc = __builtin_amdgcn_mfma_f32_32x32x16_bf16(Ah[c], bh, acc, 0, 0, 0);
            acc = __builtin_amdgcn_mfma_f32_32x32x16_bf16(Al[c], bh, acc, 0, 0, 0);
        }
#pragma unroll
        for (int c = 0; c < 12; ++c) {
            const bf16x8 bl = *(const bf16x8*)(const void*)&Bl_s[bbase + c * 16];
            acc = __builtin_amdgcn_mfma_f32_32x32x16_bf16(Ah[c], bl, acc, 0, 0, 0);
        }
        // dist tile: C layout col=lane&31, row=(reg&3)+8*(reg>>2)+4*(lane>>5)
        const int colg = wc * 32 + l31;
        const float cs = csq_s[colg];
#pragma unroll
        for (int reg = 0; reg < 16; ++reg) {
            const int rl = wr * 32 + (reg & 3) + 8 * (reg >> 2) + 4 * lhi;
            dtile[rl * 65 + colg] = rsq_s[rl] + cs - 2.0f * acc[reg];
        }
        __syncthreads();
        // scan: thread = (row p, col-segment s of 16)
        {
            const int p = tid & 63;
            const int s = tid >> 6;
#pragma unroll
            for (int t = 0; t < 16; ++t) {
                const int ml = s * 16 + t;
                ins12(t12d, t12i, dtile[p * 65 + ml], c0 + ml);
            }
        }
    }

    // dump per-thread lists (cd/ci alias the staging region — safe after scans)
    {
        const int p = tid & 63;
        const int s = tid >> 6;
#pragma unroll
        for (int q = 0; q < 12; ++q) {
            cd[CDI(s, p, q)] = t12d[q];
            ci[CDI(s, p, q)] = t12i[q];
        }
    }
    __syncthreads();
    if (tid < 64) {
        float fd[12]; int fi[12];
#pragma unroll
        for (int q = 0; q < 12; ++q) { fd[q] = 3.4e38f; fi[q] = 0x7fffffff; }
        for (int s = 0; s < 4; ++s)
#pragma unroll
            for (int q = 0; q < 12; ++q)
                ins12(fd, fi, cd[CDI(s, tid, q)], ci[CDI(s, tid, q)]);
#pragma unroll
        for (int q = 0; q < 12; ++q) ci[CDI(0, tid, q)] = fi[q];
    }
    __syncthreads();
    // fp64 re-rank of the 12 candidates (4 threads/row x 3 cands)
    {
        const int p = tid >> 2;
        const int s = tid & 3;
        const float* xr = xb + (size_t)(r0 + p) * CC;
#pragma unroll
        for (int t = 0; t < 3; ++t) {
            const int cs2 = s + t * 4;
            const int m   = ci[CDI(0, p, cs2)];
            const float* xm = xb + (size_t)m * CC;
            double dot = 0.0, sqm = 0.0, sqn = 0.0;
            for (int c = 0; c < CC; ++c) {
                const double a  = (double)xr[c];
                const double b2 = (double)xm[c];
                dot += a * b2;
                sqm += b2 * b2;
                sqn += a * a;
            }
            dd[p * 13 + cs2] = sqn + sqm - 2.0 * dot;
        }
    }
    __syncthreads();
    if (tid < 64) {
        double fd[9]; int fi[9];
#pragma unroll
        for (int q = 0; q < 9; ++q) { fd[q] = 1e300; fi[q] = 0x7fffffff; }
#pragma unroll
        for (int cs2 = 0; cs2 < 12; ++cs2)
            ins9d(fd, fi, dd[tid * 13 + cs2], ci[CDI(0, tid, cs2)]);
#pragma unroll
        for (int q = 0; q < 9; ++q)
            idxout[((size_t)b * NPTS + r0 + tid) * KNN + q] = fi[q];
    }
}

// ---------------------------------------------------------------------------
// K3a: Wcat[0:192][c]   = W1 - W2   (u weights)
//      Wcat[192:384][c] = W2        (v weights)
// ---------------------------------------------------------------------------
__global__ __launch_bounds__(256) void k3a_wcat(const float* __restrict__ cw,
                                                float* __restrict__ Wcat) {
    const int i = blockIdx.x * 256 + threadIdx.x;
    if (i < OUTC * CC) {
        const int o = i / CC, c = i - o * CC;
        const float w1 = cw[o * (2 * CC) + c];
        const float w2 = cw[o * (2 * CC) + CC + c];
        Wcat[o * CC + c]          = w1 - w2;
        Wcat[(OUTC + o) * CC + c] = w2;
    }
}

// ---------------------------------------------------------------------------
// K3b: uv[m][0:192] = norm[m]*(xn[m]·(W1-W2)^T)+b ; uv[m][192:384] = norm[m]*(xn[m]·W2^T)
// ---------------------------------------------------------------------------
__global__ __launch_bounds__(256) void k3_gemm(const float* __restrict__ xn,
                                               const float* __restrict__ Wcat,
                                               const float* __restrict__ normv,
                                               const float* __restrict__ conv_b,
                                               float* __restrict__ uv) {
    const int m0 = blockIdx.x * 64;
    const int o0 = blockIdx.y * 64;
    __shared__ __align__(16) float As[64 * 20];
    __shared__ __align__(16) float Bs[64 * 20];
    const int tid = threadIdx.x;
    const int tx  = tid & 15;
    const int ty  = tid >> 4;
    float acc[4][4] = {};

    for (int k0 = 0; k0 < CC; k0 += 16) {
        __syncthreads();
        const int row = tid >> 2;
        const int k4  = (tid & 3) << 2;
        *(float4*)&As[row * 20 + k4] = *(const float4*)&xn[(size_t)(m0 + row) * CC + k0 + k4];
        *(float4*)&Bs[row * 20 + k4] = *(const float4*)&Wcat[(size_t)(o0 + row) * CC + k0 + k4];
        __syncthreads();
#pragma unroll
        for (int kk = 0; kk < 16; kk += 4) {
            float4 av[4], bv[4];
#pragma unroll
            for (int i = 0; i < 4; ++i) av[i] = *(const float4*)&As[(i * 16 + ty) * 20 + kk];
#pragma unroll
            for (int j = 0; j < 4; ++j) bv[j] = *(const float4*)&Bs[(j * 16 + tx) * 20 + kk];
#pragma unroll
            for (int i = 0; i < 4; ++i)
#pragma unroll
                for (int j = 0; j < 4; ++j)
                    acc[i][j] += av[i].x * bv[j].x + av[i].y * bv[j].y +
                                 av[i].z * bv[j].z + av[i].w * bv[j].w;
        }
    }
    float nrm[4];
#pragma unroll
    for (int i = 0; i < 4; ++i) nrm[i] = normv[m0 + i * 16 + ty];
#pragma unroll
    for (int i = 0; i < 4; ++i)
#pragma unroll
        for (int j = 0; j < 4; ++j) {
            const int o = o0 + j * 16 + tx;
            float vvv = acc[i][j] * nrm[i];
            if (o < OUTC) vvv += conv_b[o];
            uv[(size_t)(m0 + i * 16 + ty) * (2 * OUTC) + o] = vvv;
        }
}

// ---------------------------------------------------------------------------
// K4a: per-block partial BN sums over y = u + v[idx]
// ---------------------------------------------------------------------------
__global__ __launch_bounds__(192) void k4_stats(const float* __restrict__ uv,
                                                const int* __restrict__ idxb,
                                                float* __restrict__ partials) {
    const int b  = blockIdx.y;
    const int n0 = blockIdx.x * 64;
    const int o  = threadIdx.x;
    const size_t base = (size_t)b * NPTS;
    float aS = 0.f, aQ = 0.f;
    for (int p = 0; p < 64; ++p) {
        const int n = n0 + p;
        const float u = uv[(base + n) * (2 * OUTC) + o];
        const int* ix = &idxb[(base + n) * KNN];
#pragma unroll
        for (int k = 0; k < KNN; ++k) {
            const int m  = ix[k];
            const float v = uv[(base + m) * (2 * OUTC) + OUTC + o];
            const float y = u + v;
            aS += y;
            aQ += y * y;
        }
    }
    const int blk = blockIdx.y * NTILES + blockIdx.x;
    partials[(size_t)blk * (2 * OUTC) + o]         = aS;
    partials[(size_t)blk * (2 * OUTC) + OUTC + o]  = aQ;
}

// ---------------------------------------------------------------------------
// K4b: reduce partials deterministically -> scale/shift per channel
// ---------------------------------------------------------------------------
__global__ __launch_bounds__(192) void k4b_finalize(const float* __restrict__ partials,
                                                    const float* __restrict__ gamma,
                                                    const float* __restrict__ beta,
                                                    float* __restrict__ scsh) {
    const int o = threadIdx.x;
    float S = 0.f, Q = 0.f;
    for (int blk = 0; blk < BB * NTILES; ++blk) {
        S += partials[(size_t)blk * (2 * OUTC) + o];
        Q += partials[(size_t)blk * (2 * OUTC) + OUTC + o];
    }
    const float cnt  = (float)BB * (float)NPTS * (float)KNN;
    const float mean = S / cnt;
    float var = Q / cnt - mean * mean;
    var = fmaxf(var, 0.0f);
    const float scale = gamma[o] * rsqrtf(var + 1e-5f);
    scsh[o]        = scale;
    scsh[OUTC + o] = beta[o] - mean * scale;
}

// ---------------------------------------------------------------------------
// K5: out[b][o][n] = max_k gelu((u+v[idx])*scale + shift)
// ---------------------------------------------------------------------------
__global__ __launch_bounds__(256) void k5_final(const float* __restrict__ uv,
                                                const int* __restrict__ idxb,
                                                const float* __restrict__ scsh,
                                                float* __restrict__ out) {
    const int b  = blockIdx.y;
    const int n0 = blockIdx.x * 64;
    __shared__ float zb[64 * 193];
    __shared__ float ssc[OUTC];
    __shared__ float ssh[OUTC];
    const int tid = threadIdx.x;
    for (int q = tid; q < OUTC; q += 256) {
        ssc[q] = scsh[q];
        ssh[q] = scsh[OUTC + q];
    }
    __syncthreads();
    const int p  = tid >> 2;
    const int og = tid & 3;
    const size_t base = (size_t)b * NPTS;
    const int n = n0 + p;
    float zmax[48];
#pragma unroll
    for (int t = 0; t < 48; ++t) zmax[t] = -3.4e38f;
    const float* ur = &uv[(base + n) * (2 * OUTC) + og * 48];
    const int* ix = &idxb[(base + n) * KNN];
#pragma unroll
    for (int k = 0; k < KNN; ++k) {
        const int m = ix[k];
        const float* vrow = &uv[(base + m) * (2 * OUTC) + OUTC + og * 48];
#pragma unroll
        for (int t4 = 0; t4 < 12; ++t4) {
            const float4 uu = *(const float4*)&ur[t4 * 4];
            const float4 vv = *(const float4*)&vrow[t4 * 4];
            const int ob = og * 48 + t4 * 4;
            float y, z, g;
            y = uu.x + vv.x; z = y * ssc[ob + 0] + ssh[ob + 0];
            g = 0.5f * z * (1.0f + erff(z * 0.70710678118654752f));
            zmax[t4 * 4 + 0] = fmaxf(zmax[t4 * 4 + 0], g);
            y = uu.y + vv.y; z = y * ssc[ob + 1] + ssh[ob + 1];
            g = 0.5f * z * (1.0f + erff(z * 0.70710678118654752f));
            zmax[t4 * 4 + 1] = fmaxf(zmax[t4 * 4 + 1], g);
            y = uu.z + vv.z; z = y * ssc[ob + 2] + ssh[ob + 2];
            g = 0.5f * z * (1.0f + erff(z * 0.70710678118654752f));
            zmax[t4 * 4 + 2] = fmaxf(zmax[t4 * 4 + 2], g);
            y = uu.w + vv.w; z = y * ssc[ob + 3] + ssh[ob + 3];
            g = 0.5f * z * (1.0f + erff(z * 0.70710678118654752f));
            zmax[t4 * 4 + 3] = fmaxf(zmax[t4 * 4 + 3], g);
        }
    }
#pragma unroll
    for (int t = 0; t < 48; ++t) zb[p * 193 + og * 48 + t] = zmax[t];
    __syncthreads();
    float* ob2 = out + (size_t)b * OUTC * NPTS;
    for (int q = tid; q < 64 * OUTC; q += 256) {
        const int o  = q >> 6;
        const int pp = q & 63;
        ob2[(size_t)o * NPTS + n0 + pp] = zb[pp * 193 + o];
    }
}

// ---------------------------------------------------------------------------
extern "C" void kernel_launch(void* const* d_in, const int* in_sizes, int n_in,
                              void* d_out, int out_size, void* d_ws, size_t ws_size,
                              hipStream_t stream) {
    const float* x        = (const float*)d_in[0];
    const float* conv_w   = (const float*)d_in[1];
    const float* conv_b   = (const float*)d_in[2];
    const float* bn_gamma = (const float*)d_in[3];
    const float* bn_beta  = (const float*)d_in[4];
    float* out = (float*)d_out;

    // workspace layout (floats)
    float* ws = (float*)d_ws;
    const size_t SZ_XN = (size_t)BB * NPTS * CC;        // 4,816,896
    const size_t SZ_NV = (size_t)BB * NPTS;             // 25,088
    float* xn       = ws;
    float* normv    = xn + SZ_XN;
    float* sqv      = normv + SZ_NV;
    int*   idxb     = (int*)(sqv + SZ_NV);              // B*N*K ints
    float* Wcat     = (float*)(idxb + (size_t)BB * NPTS * KNN);
    float* uv       = Wcat + (size_t)(2 * OUTC) * CC;
    float* partials = uv + (size_t)BB * NPTS * (2 * OUTC);
    float* scsh     = partials + (size_t)BB * NTILES * (2 * OUTC);
    unsigned short* xh = (unsigned short*)(scsh + 2 * OUTC);
    unsigned short* xl = xh + SZ_XN;

    k1_normalize<<<dim3(NTILES, BB), 256, 0, stream>>>(x, xn, xh, xl, normv, sqv);
    k2_knn<<<dim3(NTILES, BB), 256, 0, stream>>>(xn, xh, xl, sqv, idxb);
    k3a_wcat<<<(OUTC * CC + 255) / 256, 256, 0, stream>>>(conv_w, Wcat);
    k3_gemm<<<dim3(BB * NPTS / 64, (2 * OUTC) / 64), 256, 0, stream>>>(xn, Wcat, normv, conv_b, uv);
    k4_stats<<<dim3(NTILES, BB), 192, 0, stream>>>(uv, idxb, partials);
    k4b_finalize<<<1, 192, 0, stream>>>(partials, bn_gamma, bn_beta, scsh);
    k5_final<<<dim3(NTILES, BB), 256, 0, stream>>>(uv, idxb, scsh, out);
}

// Round 3
// 1296.386 us; speedup vs baseline: 3.0908x; 2.5306x over previous
//
#include <hip/hip_runtime.h>
#include <hip/hip_bf16.h>
#include <math.h>

// Problem constants
#define BB 8
#define CC 192
#define HH 56
#define WW 56
#define NPTS 3136        // H*W
#define OUTC 192
#define KNN 9
#define NTILES 49        // NPTS/64
#define NCH 2            // column chunks (chunk0: tiles 0..24, chunk1: 25..48)

typedef __bf16 bf16x8 __attribute__((ext_vector_type(8)));
typedef float  f32x16 __attribute__((ext_vector_type(16)));

__device__ __forceinline__ unsigned short f2bf(float f) {
    unsigned u = __float_as_uint(f);
    u += 0x7fffu + ((u >> 16) & 1u);       // RNE
    return (unsigned short)(u >> 16);
}
__device__ __forceinline__ float bf2f(unsigned short h) {
    return __uint_as_float(((unsigned)h) << 16);
}

// sorted-ascending top-12 of u64 keys ((distbits<<32)|idx -> lexicographic)
__device__ __forceinline__ void ins12u(unsigned long long (&t)[12], unsigned long long key) {
    if (key >= t[11]) return;
    t[11] = key;
#pragma unroll
    for (int q = 11; q > 0; --q) {
        const unsigned long long a = t[q-1], bq = t[q];
        const bool sw = bq < a;
        t[q-1] = sw ? bq : a;
        t[q]   = sw ? a : bq;
    }
}

__device__ __forceinline__ void ins9d(double (&d)[9], int (&ix)[9], double nd, int ni) {
    if (!((nd < d[8]) || (nd == d[8] && ni < ix[8]))) return;
    d[8] = nd; ix[8] = ni;
#pragma unroll
    for (int q = 8; q > 0; --q) {
        if ((d[q] < d[q-1]) || (d[q] == d[q-1] && ix[q] < ix[q-1])) {
            double t = d[q]; d[q] = d[q-1]; d[q-1] = t;
            int t2 = ix[q]; ix[q] = ix[q-1]; ix[q-1] = t2;
        }
    }
}

// ---------------------------------------------------------------------------
// K1: transpose (B,C,N)->(B,N,C), L2-normalize rows; emit xn (f32),
//     xh/xl (bf16 hi/lo split of xn), norm, sq(xn)
// ---------------------------------------------------------------------------
__global__ __launch_bounds__(256) void k1_normalize(const float* __restrict__ x,
                                                    float* __restrict__ xn,
                                                    unsigned short* __restrict__ xh,
                                                    unsigned short* __restrict__ xl,
                                                    float* __restrict__ normv,
                                                    float* __restrict__ sqv) {
    const int b  = blockIdx.y;
    const int n0 = blockIdx.x * 64;
    __shared__ float tile[64 * 193];
    __shared__ float red[4][64];
    __shared__ float inv[64];
    const int tid = threadIdx.x;
    const int p   = tid & 63;
    const int cg  = tid >> 6;
    const float* xb = x + (size_t)b * CC * NPTS;

    float acc = 0.f;
#pragma unroll 4
    for (int t = 0; t < 48; ++t) {
        const int c = cg * 48 + t;
        const float v = xb[(size_t)c * NPTS + n0 + p];
        tile[p * 193 + c] = v;
        acc += v * v;
    }
    red[cg][p] = acc;
    __syncthreads();
    if (cg == 0) {
        const float s  = red[0][p] + red[1][p] + red[2][p] + red[3][p];
        float nc = sqrtf(s);
        nc = fmaxf(nc, 1e-12f);
        normv[b * NPTS + n0 + p] = nc;
        const float iv = 1.0f / nc;
        inv[p] = iv;
        sqv[b * NPTS + n0 + p] = s * iv * iv;
    }
    __syncthreads();
    const size_t base = ((size_t)b * NPTS + n0) * CC;
    float* dst = xn + base;
    for (int q = tid; q < 64 * CC / 4; q += 256) {
        const int f   = q * 4;
        const int row = f / CC;
        const int c   = f - row * CC;
        const float iv = inv[row];
        float4 v;
        v.x = tile[row * 193 + c + 0] * iv;
        v.y = tile[row * 193 + c + 1] * iv;
        v.z = tile[row * 193 + c + 2] * iv;
        v.w = tile[row * 193 + c + 3] * iv;
        *(float4*)&dst[f] = v;
        ushort4 hv, lv;
        hv.x = f2bf(v.x); lv.x = f2bf(v.x - bf2f(hv.x));
        hv.y = f2bf(v.y); lv.y = f2bf(v.y - bf2f(hv.y));
        hv.z = f2bf(v.z); lv.z = f2bf(v.z - bf2f(hv.z));
        hv.w = f2bf(v.w); lv.w = f2bf(v.w - bf2f(hv.w));
        *(ushort4*)&xh[base + f] = hv;
        *(ushort4*)&xl[base + f] = lv;
    }
}

// ---------------------------------------------------------------------------
// K2: MFMA split-bf16 cosine-distance GEMM + u64-key top-12 per column chunk.
// grid (49 row-tiles, 2 chunks, 8 batches), block 256.
// Writes per-row sorted top-12 u64 keys to pd[b][row][chunk][12].
// ---------------------------------------------------------------------------
__global__ __launch_bounds__(256, 3) void k2_knn(const unsigned short* __restrict__ xh,
                                                 const unsigned short* __restrict__ xl,
                                                 const float* __restrict__ sqv,
                                                 unsigned long long* __restrict__ pd) {
    const int b     = blockIdx.z;
    const int chunk = blockIdx.y;
    const int r0    = blockIdx.x * 64;
    const int t0    = chunk ? 25 : 0;
    const int t1    = chunk ? 49 : 25;

    __shared__ __align__(16) char smem[51712];
    unsigned short* Bh_s = (unsigned short*)smem;             // 64 rows * 200 shorts
    unsigned short* Bl_s = (unsigned short*)(smem + 25600);   // 64 * 200
    unsigned long long* dtile = (unsigned long long*)smem;    // alias [0, 33280): u64[64][65]
    float* rsq_s = (float*)(smem + 51200);                    // 64 f32
    float* csq_s = (float*)(smem + 51456);                    // 64 f32
    unsigned long long* cd64 = (unsigned long long*)smem;     // alias [0, 24576): [4][64][12]

    const int tid  = threadIdx.x;
    const int w    = tid >> 6;
    const int lane = tid & 63;
    const int wr   = w >> 1, wc = w & 1;
    const int l31  = lane & 31;
    const int lhi  = lane >> 5;
    const int koffe = lhi * 8;

    // A fragments in registers: rows r0 + wr*32 + l31
    const size_t abase = ((size_t)b * NPTS + (r0 + wr * 32 + l31)) * CC;
    bf16x8 Ah[12], Al[12];
#pragma unroll
    for (int c = 0; c < 12; ++c) {
        Ah[c] = *(const bf16x8*)(const void*)(xh + abase + c * 16 + koffe);
        Al[c] = *(const bf16x8*)(const void*)(xl + abase + c * 16 + koffe);
    }
    if (tid < 64) rsq_s[tid] = sqv[b * NPTS + r0 + tid];

    unsigned long long t12[12];
#pragma unroll
    for (int q = 0; q < 12; ++q) t12[q] = 0xFFFFFFFFFFFFFFFFull;

    for (int ct = t0; ct < t1; ++ct) {
        const int c0 = ct * 64;
        __syncthreads();   // prev scan reads done before staging clobbers dtile/B
        if (tid < 64) csq_s[tid] = sqv[b * NPTS + c0 + tid];
#pragma unroll
        for (int rep = 0; rep < 6; ++rep) {
            const int cidx  = rep * 256 + tid;
            const int point = cidx / 24;
            const int c8    = cidx - point * 24;
            const size_t g  = ((size_t)b * NPTS + c0 + point) * CC + c8 * 8;
            *(uint4*)(void*)&Bh_s[point * 200 + c8 * 8] = *(const uint4*)(const void*)(xh + g);
            *(uint4*)(void*)&Bl_s[point * 200 + c8 * 8] = *(const uint4*)(const void*)(xl + g);
        }
        __syncthreads();   // staged

        f32x16 acc;
#pragma unroll
        for (int r = 0; r < 16; ++r) acc[r] = 0.f;
        const int bbase = (wc * 32 + l31) * 200 + koffe;
#pragma unroll
        for (int c = 0; c < 12; ++c) {
            const bf16x8 bh = *(const bf16x8*)(const void*)&Bh_s[bbase + c * 16];
            acc = __builtin_amdgcn_mfma_f32_32x32x16_bf16(Ah[c], bh, acc, 0, 0, 0);
            acc = __builtin_amdgcn_mfma_f32_32x32x16_bf16(Al[c], bh, acc, 0, 0, 0);
        }
#pragma unroll
        for (int c = 0; c < 12; ++c) {
            const bf16x8 bl = *(const bf16x8*)(const void*)&Bl_s[bbase + c * 16];
            acc = __builtin_amdgcn_mfma_f32_32x32x16_bf16(Ah[c], bl, acc, 0, 0, 0);
        }
        __syncthreads();   // all B ds_reads done before dtile write clobbers B
        // pack (dist,col) u64 keys into dtile
        const int colg = wc * 32 + l31;
        const float cs = csq_s[colg];
#pragma unroll
        for (int reg = 0; reg < 16; ++reg) {
            const int rl = wr * 32 + (reg & 3) + 8 * (reg >> 2) + 4 * lhi;
            const float dv = fmaxf(rsq_s[rl] + cs - 2.0f * acc[reg], 0.0f);
            dtile[rl * 65 + colg] =
                ((unsigned long long)__float_as_uint(dv) << 32) | (unsigned)(c0 + colg);
        }
        __syncthreads();   // dtile visible
        // scan: thread = (row p, col-segment s of 16)
        {
            const unsigned long long* drow = dtile + (size_t)(tid & 63) * 65 + (tid >> 6) * 16;
#pragma unroll
            for (int t = 0; t < 16; ++t) ins12u(t12, drow[t]);
        }
    }

    __syncthreads();       // last scan done before cd64 overwrites dtile region
    {
        const int p = tid & 63;
        const int s = tid >> 6;
#pragma unroll
        for (int q = 0; q < 12; ++q) cd64[(s * 64 + p) * 12 + q] = t12[q];
    }
    __syncthreads();
    if (tid < 64) {
        unsigned long long t[12];
#pragma unroll
        for (int q = 0; q < 12; ++q) t[q] = cd64[tid * 12 + q];
        for (int s = 1; s < 4; ++s)
#pragma unroll
            for (int q = 0; q < 12; ++q) ins12u(t, cd64[(s * 64 + tid) * 12 + q]);
        const size_t gbase = ((size_t)b * NPTS + r0 + tid) * (NCH * 12) + chunk * 12;
#pragma unroll
        for (int q = 0; q < 12; ++q) pd[gbase + q] = t[q];
    }
}

// ---------------------------------------------------------------------------
// K2b: merge chunk lists -> top-12, fp64 re-rank -> idx[b,n,9]
// grid (49, 8), block 256
// ---------------------------------------------------------------------------
__global__ __launch_bounds__(256) void k2b_merge(const float* __restrict__ xn,
                                                 const unsigned long long* __restrict__ pd,
                                                 int* __restrict__ idxout) {
    const int b  = blockIdx.y;
    const int r0 = blockIdx.x * 64;
    __shared__ int    ci[64][12];
    __shared__ double dd[64][13];
    const int tid = threadIdx.x;
    if (tid < 64) {
        const size_t base = ((size_t)b * NPTS + r0 + tid) * (NCH * 12);
        unsigned long long t[12];
#pragma unroll
        for (int q = 0; q < 12; ++q) t[q] = pd[base + q];
#pragma unroll
        for (int q = 0; q < 12; ++q) ins12u(t, pd[base + 12 + q]);
#pragma unroll
        for (int q = 0; q < 12; ++q) ci[tid][q] = (int)(unsigned)t[q];
    }
    __syncthreads();
    const float* xb = xn + (size_t)b * NPTS * CC;
    {
        const int p = tid >> 2;
        const int s = tid & 3;
        const float* xr = xb + (size_t)(r0 + p) * CC;
#pragma unroll
        for (int t3 = 0; t3 < 3; ++t3) {
            const int cs2 = s + t3 * 4;
            const int m   = ci[p][cs2];
            const float* xm = xb + (size_t)m * CC;
            double dot = 0.0, sqm = 0.0, sqn = 0.0;
            for (int c = 0; c < CC; ++c) {
                const double a  = (double)xr[c];
                const double b2 = (double)xm[c];
                dot += a * b2;
                sqm += b2 * b2;
                sqn += a * a;
            }
            dd[p][cs2] = sqn + sqm - 2.0 * dot;
        }
    }
    __syncthreads();
    if (tid < 64) {
        double fd[9]; int fi[9];
#pragma unroll
        for (int q = 0; q < 9; ++q) { fd[q] = 1e300; fi[q] = 0x7fffffff; }
#pragma unroll
        for (int cs2 = 0; cs2 < 12; ++cs2)
            ins9d(fd, fi, dd[tid][cs2], ci[tid][cs2]);
#pragma unroll
        for (int q = 0; q < 9; ++q)
            idxout[((size_t)b * NPTS + r0 + tid) * KNN + q] = fi[q];
    }
}

// ---------------------------------------------------------------------------
// K3a: Wcat[0:192][c] = W1 - W2 ; Wcat[192:384][c] = W2
// ---------------------------------------------------------------------------
__global__ __launch_bounds__(256) void k3a_wcat(const float* __restrict__ cw,
                                                float* __restrict__ Wcat) {
    const int i = blockIdx.x * 256 + threadIdx.x;
    if (i < OUTC * CC) {
        const int o = i / CC, c = i - o * CC;
        const float w1 = cw[o * (2 * CC) + c];
        const float w2 = cw[o * (2 * CC) + CC + c];
        Wcat[o * CC + c]          = w1 - w2;
        Wcat[(OUTC + o) * CC + c] = w2;
    }
}

// ---------------------------------------------------------------------------
// K3b: uv[m][0:192] = norm[m]*(xn[m]·(W1-W2)^T)+b ; uv[m][192:384] = norm[m]*(xn[m]·W2^T)
// ---------------------------------------------------------------------------
__global__ __launch_bounds__(256) void k3_gemm(const float* __restrict__ xn,
                                               const float* __restrict__ Wcat,
                                               const float* __restrict__ normv,
                                               const float* __restrict__ conv_b,
                                               float* __restrict__ uv) {
    const int m0 = blockIdx.x * 64;
    const int o0 = blockIdx.y * 64;
    __shared__ __align__(16) float As[64 * 20];
    __shared__ __align__(16) float Bs[64 * 20];
    const int tid = threadIdx.x;
    const int tx  = tid & 15;
    const int ty  = tid >> 4;
    float acc[4][4] = {};

    for (int k0 = 0; k0 < CC; k0 += 16) {
        __syncthreads();
        const int row = tid >> 2;
        const int k4  = (tid & 3) << 2;
        *(float4*)&As[row * 20 + k4] = *(const float4*)&xn[(size_t)(m0 + row) * CC + k0 + k4];
        *(float4*)&Bs[row * 20 + k4] = *(const float4*)&Wcat[(size_t)(o0 + row) * CC + k0 + k4];
        __syncthreads();
#pragma unroll
        for (int kk = 0; kk < 16; kk += 4) {
            float4 av[4], bv[4];
#pragma unroll
            for (int i = 0; i < 4; ++i) av[i] = *(const float4*)&As[(i * 16 + ty) * 20 + kk];
#pragma unroll
            for (int j = 0; j < 4; ++j) bv[j] = *(const float4*)&Bs[(j * 16 + tx) * 20 + kk];
#pragma unroll
            for (int i = 0; i < 4; ++i)
#pragma unroll
                for (int j = 0; j < 4; ++j)
                    acc[i][j] += av[i].x * bv[j].x + av[i].y * bv[j].y +
                                 av[i].z * bv[j].z + av[i].w * bv[j].w;
        }
    }
    float nrm[4];
#pragma unroll
    for (int i = 0; i < 4; ++i) nrm[i] = normv[m0 + i * 16 + ty];
#pragma unroll
    for (int i = 0; i < 4; ++i)
#pragma unroll
        for (int j = 0; j < 4; ++j) {
            const int o = o0 + j * 16 + tx;
            float vvv = acc[i][j] * nrm[i];
            if (o < OUTC) vvv += conv_b[o];
            uv[(size_t)(m0 + i * 16 + ty) * (2 * OUTC) + o] = vvv;
        }
}

// ---------------------------------------------------------------------------
// K4a: per-block partial BN sums over y = u + v[idx]
// ---------------------------------------------------------------------------
__global__ __launch_bounds__(192) void k4_stats(const float* __restrict__ uv,
                                                const int* __restrict__ idxb,
                                                float* __restrict__ partials) {
    const int b  = blockIdx.y;
    const int n0 = blockIdx.x * 64;
    const int o  = threadIdx.x;
    const size_t base = (size_t)b * NPTS;
    float aS = 0.f, aQ = 0.f;
    for (int p = 0; p < 64; ++p) {
        const int n = n0 + p;
        const float u = uv[(base + n) * (2 * OUTC) + o];
        const int* ix = &idxb[(base + n) * KNN];
#pragma unroll
        for (int k = 0; k < KNN; ++k) {
            const int m  = ix[k];
            const float v = uv[(base + m) * (2 * OUTC) + OUTC + o];
            const float y = u + v;
            aS += y;
            aQ += y * y;
        }
    }
    const int blk = blockIdx.y * NTILES + blockIdx.x;
    partials[(size_t)blk * (2 * OUTC) + o]         = aS;
    partials[(size_t)blk * (2 * OUTC) + OUTC + o]  = aQ;
}

// ---------------------------------------------------------------------------
// K4b: reduce partials deterministically -> scale/shift per channel
// ---------------------------------------------------------------------------
__global__ __launch_bounds__(192) void k4b_finalize(const float* __restrict__ partials,
                                                    const float* __restrict__ gamma,
                                                    const float* __restrict__ beta,
                                                    float* __restrict__ scsh) {
    const int o = threadIdx.x;
    float S = 0.f, Q = 0.f;
    for (int blk = 0; blk < BB * NTILES; ++blk) {
        S += partials[(size_t)blk * (2 * OUTC) + o];
        Q += partials[(size_t)blk * (2 * OUTC) + OUTC + o];
    }
    const float cnt  = (float)BB * (float)NPTS * (float)KNN;
    const float mean = S / cnt;
    float var = Q / cnt - mean * mean;
    var = fmaxf(var, 0.0f);
    const float scale = gamma[o] * rsqrtf(var + 1e-5f);
    scsh[o]        = scale;
    scsh[OUTC + o] = beta[o] - mean * scale;
}

// ---------------------------------------------------------------------------
// K5: out[b][o][n] = max_k gelu((u+v[idx])*scale + shift)
// ---------------------------------------------------------------------------
__global__ __launch_bounds__(256) void k5_final(const float* __restrict__ uv,
                                                const int* __restrict__ idxb,
                                                const float* __restrict__ scsh,
                                                float* __restrict__ out) {
    const int b  = blockIdx.y;
    const int n0 = blockIdx.x * 64;
    __shared__ float zb[64 * 193];
    __shared__ float ssc[OUTC];
    __shared__ float ssh[OUTC];
    const int tid = threadIdx.x;
    for (int q = tid; q < OUTC; q += 256) {
        ssc[q] = scsh[q];
        ssh[q] = scsh[OUTC + q];
    }
    __syncthreads();
    const int p  = tid >> 2;
    const int og = tid & 3;
    const size_t base = (size_t)b * NPTS;
    const int n = n0 + p;
    float zmax[48];
#pragma unroll
    for (int t = 0; t < 48; ++t) zmax[t] = -3.4e38f;
    const float* ur = &uv[(base + n) * (2 * OUTC) + og * 48];
    const int* ix = &idxb[(base + n) * KNN];
#pragma unroll
    for (int k = 0; k < KNN; ++k) {
        const int m = ix[k];
        const float* vrow = &uv[(base + m) * (2 * OUTC) + OUTC + og * 48];
#pragma unroll
        for (int t4 = 0; t4 < 12; ++t4) {
            const float4 uu = *(const float4*)&ur[t4 * 4];
            const float4 vv = *(const float4*)&vrow[t4 * 4];
            const int ob = og * 48 + t4 * 4;
            float y, z, g;
            y = uu.x + vv.x; z = y * ssc[ob + 0] + ssh[ob + 0];
            g = 0.5f * z * (1.0f + erff(z * 0.70710678118654752f));
            zmax[t4 * 4 + 0] = fmaxf(zmax[t4 * 4 + 0], g);
            y = uu.y + vv.y; z = y * ssc[ob + 1] + ssh[ob + 1];
            g = 0.5f * z * (1.0f + erff(z * 0.70710678118654752f));
            zmax[t4 * 4 + 1] = fmaxf(zmax[t4 * 4 + 1], g);
            y = uu.z + vv.z; z = y * ssc[ob + 2] + ssh[ob + 2];
            g = 0.5f * z * (1.0f + erff(z * 0.70710678118654752f));
            zmax[t4 * 4 + 2] = fmaxf(zmax[t4 * 4 + 2], g);
            y = uu.w + vv.w; z = y * ssc[ob + 3] + ssh[ob + 3];
            g = 0.5f * z * (1.0f + erff(z * 0.70710678118654752f));
            zmax[t4 * 4 + 3] = fmaxf(zmax[t4 * 4 + 3], g);
        }
    }
#pragma unroll
    for (int t = 0; t < 48; ++t) zb[p * 193 + og * 48 + t] = zmax[t];
    __syncthreads();
    float* ob2 = out + (size_t)b * OUTC * NPTS;
    for (int q = tid; q < 64 * OUTC; q += 256) {
        const int o  = q >> 6;
        const int pp = q & 63;
        ob2[(size_t)o * NPTS + n0 + pp] = zb[pp * 193 + o];
    }
}

// ---------------------------------------------------------------------------
extern "C" void kernel_launch(void* const* d_in, const int* in_sizes, int n_in,
                              void* d_out, int out_size, void* d_ws, size_t ws_size,
                              hipStream_t stream) {
    const float* x        = (const float*)d_in[0];
    const float* conv_w   = (const float*)d_in[1];
    const float* conv_b   = (const float*)d_in[2];
    const float* bn_gamma = (const float*)d_in[3];
    const float* bn_beta  = (const float*)d_in[4];
    float* out = (float*)d_out;

    // workspace layout (floats)
    float* ws = (float*)d_ws;
    const size_t SZ_XN = (size_t)BB * NPTS * CC;
    const size_t SZ_NV = (size_t)BB * NPTS;
    float* xn       = ws;
    float* normv    = xn + SZ_XN;
    float* sqv      = normv + SZ_NV;
    int*   idxb     = (int*)(sqv + SZ_NV);
    float* Wcat     = (float*)(idxb + (size_t)BB * NPTS * KNN);
    float* uv       = Wcat + (size_t)(2 * OUTC) * CC;
    float* partials = uv + (size_t)BB * NPTS * (2 * OUTC);
    float* scsh     = partials + (size_t)BB * NTILES * (2 * OUTC);
    unsigned short* xh = (unsigned short*)(scsh + 2 * OUTC);
    unsigned short* xl = xh + SZ_XN;
    // pd aliases uv: k2/k2b use it before k3 writes uv (4.8 MB <= 38.5 MB)
    unsigned long long* pd = (unsigned long long*)uv;

    k1_normalize<<<dim3(NTILES, BB), 256, 0, stream>>>(x, xn, xh, xl, normv, sqv);
    k2_knn<<<dim3(NTILES, NCH, BB), 256, 0, stream>>>(xh, xl, sqv, pd);
    k2b_merge<<<dim3(NTILES, BB), 256, 0, stream>>>(xn, pd, idxb);
    k3a_wcat<<<(OUTC * CC + 255) / 256, 256, 0, stream>>>(conv_w, Wcat);
    k3_gemm<<<dim3(BB * NPTS / 64, (2 * OUTC) / 64), 256, 0, stream>>>(xn, Wcat, normv, conv_b, uv);
    k4_stats<<<dim3(NTILES, BB), 192, 0, stream>>>(uv, idxb, partials);
    k4b_finalize<<<1, 192, 0, stream>>>(partials, bn_gamma, bn_beta, scsh);
    k5_final<<<dim3(NTILES, BB), 256, 0, stream>>>(uv, idxb, scsh, out);
}

// Round 4
// 793.224 us; speedup vs baseline: 5.0515x; 1.6343x over previous
//
#include <hip/hip_runtime.h>
#include <hip/hip_bf16.h>
#include <math.h>

// Problem constants
#define BB 8
#define CC 192
#define HH 56
#define WW 56
#define NPTS 3136        // H*W
#define OUTC 192
#define KNN 9
#define NTILES 49        // NPTS/64
#define NCH 2            // k2 column chunks
#define NT4 98           // NPTS/32 (k4 tiles)
#define NBLK4 (NT4 * BB) // 784

typedef __bf16 bf16x8 __attribute__((ext_vector_type(8)));
typedef float  f32x16 __attribute__((ext_vector_type(16)));

__device__ __forceinline__ unsigned short f2bf(float f) {
    unsigned u = __float_as_uint(f);
    u += 0x7fffu + ((u >> 16) & 1u);       // RNE
    return (unsigned short)(u >> 16);
}
__device__ __forceinline__ float bf2f(unsigned short h) {
    return __uint_as_float(((unsigned)h) << 16);
}
__device__ __forceinline__ float gelu_f(float z) {
    return 0.5f * z * (1.0f + erff(z * 0.70710678118654752f));
}

// sorted-ascending top-12 of u64 keys ((distbits<<32)|idx -> lexicographic)
__device__ __forceinline__ void ins12u(unsigned long long (&t)[12], unsigned long long key) {
    if (key >= t[11]) return;
    t[11] = key;
#pragma unroll
    for (int q = 11; q > 0; --q) {
        const unsigned long long a = t[q-1], bq = t[q];
        const bool sw = bq < a;
        t[q-1] = sw ? bq : a;
        t[q]   = sw ? a : bq;
    }
}

__device__ __forceinline__ void ins9d(double (&d)[9], int (&ix)[9], double nd, int ni) {
    if (!((nd < d[8]) || (nd == d[8] && ni < ix[8]))) return;
    d[8] = nd; ix[8] = ni;
#pragma unroll
    for (int q = 8; q > 0; --q) {
        if ((d[q] < d[q-1]) || (d[q] == d[q-1] && ix[q] < ix[q-1])) {
            double t = d[q]; d[q] = d[q-1]; d[q-1] = t;
            int t2 = ix[q]; ix[q] = ix[q-1]; ix[q-1] = t2;
        }
    }
}

// ---------------------------------------------------------------------------
// K1: transpose (B,C,N)->(B,N,C), L2-normalize rows; emit xn (f32),
//     xh/xl (bf16 hi/lo split of xn), norm, sq(xn)
// ---------------------------------------------------------------------------
__global__ __launch_bounds__(256) void k1_normalize(const float* __restrict__ x,
                                                    float* __restrict__ xn,
                                                    unsigned short* __restrict__ xh,
                                                    unsigned short* __restrict__ xl,
                                                    float* __restrict__ normv,
                                                    float* __restrict__ sqv) {
    const int b  = blockIdx.y;
    const int n0 = blockIdx.x * 64;
    __shared__ float tile[64 * 193];
    __shared__ float red[4][64];
    __shared__ float inv[64];
    const int tid = threadIdx.x;
    const int p   = tid & 63;
    const int cg  = tid >> 6;
    const float* xb = x + (size_t)b * CC * NPTS;

    float acc = 0.f;
#pragma unroll 4
    for (int t = 0; t < 48; ++t) {
        const int c = cg * 48 + t;
        const float v = xb[(size_t)c * NPTS + n0 + p];
        tile[p * 193 + c] = v;
        acc += v * v;
    }
    red[cg][p] = acc;
    __syncthreads();
    if (cg == 0) {
        const float s  = red[0][p] + red[1][p] + red[2][p] + red[3][p];
        float nc = sqrtf(s);
        nc = fmaxf(nc, 1e-12f);
        normv[b * NPTS + n0 + p] = nc;
        const float iv = 1.0f / nc;
        inv[p] = iv;
        sqv[b * NPTS + n0 + p] = s * iv * iv;
    }
    __syncthreads();
    const size_t base = ((size_t)b * NPTS + n0) * CC;
    float* dst = xn + base;
    for (int q = tid; q < 64 * CC / 4; q += 256) {
        const int f   = q * 4;
        const int row = f / CC;
        const int c   = f - row * CC;
        const float iv = inv[row];
        float4 v;
        v.x = tile[row * 193 + c + 0] * iv;
        v.y = tile[row * 193 + c + 1] * iv;
        v.z = tile[row * 193 + c + 2] * iv;
        v.w = tile[row * 193 + c + 3] * iv;
        *(float4*)&dst[f] = v;
        ushort4 hv, lv;
        hv.x = f2bf(v.x); lv.x = f2bf(v.x - bf2f(hv.x));
        hv.y = f2bf(v.y); lv.y = f2bf(v.y - bf2f(hv.y));
        hv.z = f2bf(v.z); lv.z = f2bf(v.z - bf2f(hv.z));
        hv.w = f2bf(v.w); lv.w = f2bf(v.w - bf2f(hv.w));
        *(ushort4*)&xh[base + f] = hv;
        *(ushort4*)&xl[base + f] = lv;
    }
}

// ---------------------------------------------------------------------------
// K2: MFMA split-bf16 cosine-distance GEMM + u64-key top-12 per column chunk.
// grid (49 row-tiles, 2 chunks, 8 batches), block 256.
// ---------------------------------------------------------------------------
__global__ __launch_bounds__(256, 3) void k2_knn(const unsigned short* __restrict__ xh,
                                                 const unsigned short* __restrict__ xl,
                                                 const float* __restrict__ sqv,
                                                 unsigned long long* __restrict__ pd) {
    const int b     = blockIdx.z;
    const int chunk = blockIdx.y;
    const int r0    = blockIdx.x * 64;
    const int t0    = chunk ? 25 : 0;
    const int t1    = chunk ? 49 : 25;

    __shared__ __align__(16) char smem[51712];
    unsigned short* Bh_s = (unsigned short*)smem;             // 64 rows * 200 shorts
    unsigned short* Bl_s = (unsigned short*)(smem + 25600);   // 64 * 200
    unsigned long long* dtile = (unsigned long long*)smem;    // alias [0, 33280): u64[64][65]
    float* rsq_s = (float*)(smem + 51200);                    // 64 f32
    float* csq_s = (float*)(smem + 51456);                    // 64 f32
    unsigned long long* cd64 = (unsigned long long*)smem;     // alias [0, 24576): [4][64][12]

    const int tid  = threadIdx.x;
    const int w    = tid >> 6;
    const int lane = tid & 63;
    const int wr   = w >> 1, wc = w & 1;
    const int l31  = lane & 31;
    const int lhi  = lane >> 5;
    const int koffe = lhi * 8;

    const size_t abase = ((size_t)b * NPTS + (r0 + wr * 32 + l31)) * CC;
    bf16x8 Ah[12], Al[12];
#pragma unroll
    for (int c = 0; c < 12; ++c) {
        Ah[c] = *(const bf16x8*)(const void*)(xh + abase + c * 16 + koffe);
        Al[c] = *(const bf16x8*)(const void*)(xl + abase + c * 16 + koffe);
    }
    if (tid < 64) rsq_s[tid] = sqv[b * NPTS + r0 + tid];

    unsigned long long t12[12];
#pragma unroll
    for (int q = 0; q < 12; ++q) t12[q] = 0xFFFFFFFFFFFFFFFFull;

    for (int ct = t0; ct < t1; ++ct) {
        const int c0 = ct * 64;
        __syncthreads();
        if (tid < 64) csq_s[tid] = sqv[b * NPTS + c0 + tid];
#pragma unroll
        for (int rep = 0; rep < 6; ++rep) {
            const int cidx  = rep * 256 + tid;
            const int point = cidx / 24;
            const int c8    = cidx - point * 24;
            const size_t g  = ((size_t)b * NPTS + c0 + point) * CC + c8 * 8;
            *(uint4*)(void*)&Bh_s[point * 200 + c8 * 8] = *(const uint4*)(const void*)(xh + g);
            *(uint4*)(void*)&Bl_s[point * 200 + c8 * 8] = *(const uint4*)(const void*)(xl + g);
        }
        __syncthreads();

        f32x16 acc;
#pragma unroll
        for (int r = 0; r < 16; ++r) acc[r] = 0.f;
        const int bbase = (wc * 32 + l31) * 200 + koffe;
#pragma unroll
        for (int c = 0; c < 12; ++c) {
            const bf16x8 bh = *(const bf16x8*)(const void*)&Bh_s[bbase + c * 16];
            acc = __builtin_amdgcn_mfma_f32_32x32x16_bf16(Ah[c], bh, acc, 0, 0, 0);
            acc = __builtin_amdgcn_mfma_f32_32x32x16_bf16(Al[c], bh, acc, 0, 0, 0);
        }
#pragma unroll
        for (int c = 0; c < 12; ++c) {
            const bf16x8 bl = *(const bf16x8*)(const void*)&Bl_s[bbase + c * 16];
            acc = __builtin_amdgcn_mfma_f32_32x32x16_bf16(Ah[c], bl, acc, 0, 0, 0);
        }
        __syncthreads();
        const int colg = wc * 32 + l31;
        const float cs = csq_s[colg];
#pragma unroll
        for (int reg = 0; reg < 16; ++reg) {
            const int rl = wr * 32 + (reg & 3) + 8 * (reg >> 2) + 4 * lhi;
            const float dv = fmaxf(rsq_s[rl] + cs - 2.0f * acc[reg], 0.0f);
            dtile[rl * 65 + colg] =
                ((unsigned long long)__float_as_uint(dv) << 32) | (unsigned)(c0 + colg);
        }
        __syncthreads();
        {
            const unsigned long long* drow = dtile + (size_t)(tid & 63) * 65 + (tid >> 6) * 16;
#pragma unroll
            for (int t = 0; t < 16; ++t) ins12u(t12, drow[t]);
        }
    }

    __syncthreads();
    {
        const int p = tid & 63;
        const int s = tid >> 6;
#pragma unroll
        for (int q = 0; q < 12; ++q) cd64[(s * 64 + p) * 12 + q] = t12[q];
    }
    __syncthreads();
    if (tid < 64) {
        unsigned long long t[12];
#pragma unroll
        for (int q = 0; q < 12; ++q) t[q] = cd64[tid * 12 + q];
        for (int s = 1; s < 4; ++s)
#pragma unroll
            for (int q = 0; q < 12; ++q) ins12u(t, cd64[(s * 64 + tid) * 12 + q]);
        const size_t gbase = ((size_t)b * NPTS + r0 + tid) * (NCH * 12) + chunk * 12;
#pragma unroll
        for (int q = 0; q < 12; ++q) pd[gbase + q] = t[q];
    }
}

// ---------------------------------------------------------------------------
// K2b: merge chunk lists -> top-12, fp64 re-rank -> idx[b,n,9]
// ---------------------------------------------------------------------------
__global__ __launch_bounds__(256) void k2b_merge(const float* __restrict__ xn,
                                                 const unsigned long long* __restrict__ pd,
                                                 int* __restrict__ idxout) {
    const int b  = blockIdx.y;
    const int r0 = blockIdx.x * 64;
    __shared__ int    ci[64][12];
    __shared__ double dd[64][13];
    const int tid = threadIdx.x;
    if (tid < 64) {
        const size_t base = ((size_t)b * NPTS + r0 + tid) * (NCH * 12);
        unsigned long long t[12];
#pragma unroll
        for (int q = 0; q < 12; ++q) t[q] = pd[base + q];
#pragma unroll
        for (int q = 0; q < 12; ++q) ins12u(t, pd[base + 12 + q]);
#pragma unroll
        for (int q = 0; q < 12; ++q) ci[tid][q] = (int)(unsigned)t[q];
    }
    __syncthreads();
    const float* xb = xn + (size_t)b * NPTS * CC;
    {
        const int p = tid >> 2;
        const int s = tid & 3;
        const float* xr = xb + (size_t)(r0 + p) * CC;
#pragma unroll
        for (int t3 = 0; t3 < 3; ++t3) {
            const int cs2 = s + t3 * 4;
            const int m   = ci[p][cs2];
            const float* xm = xb + (size_t)m * CC;
            double dot = 0.0, sqm = 0.0, sqn = 0.0;
            for (int c = 0; c < CC; ++c) {
                const double a  = (double)xr[c];
                const double b2 = (double)xm[c];
                dot += a * b2;
                sqm += b2 * b2;
                sqn += a * a;
            }
            dd[p][cs2] = sqn + sqm - 2.0 * dot;
        }
    }
    __syncthreads();
    if (tid < 64) {
        double fd[9]; int fi[9];
#pragma unroll
        for (int q = 0; q < 9; ++q) { fd[q] = 1e300; fi[q] = 0x7fffffff; }
#pragma unroll
        for (int cs2 = 0; cs2 < 12; ++cs2)
            ins9d(fd, fi, dd[tid][cs2], ci[tid][cs2]);
#pragma unroll
        for (int q = 0; q < 9; ++q)
            idxout[((size_t)b * NPTS + r0 + tid) * KNN + q] = fi[q];
    }
}

// ---------------------------------------------------------------------------
// K3a: Wcat[0:192][c] = W1 - W2 ; Wcat[192:384][c] = W2
// ---------------------------------------------------------------------------
__global__ __launch_bounds__(256) void k3a_wcat(const float* __restrict__ cw,
                                                float* __restrict__ Wcat) {
    const int i = blockIdx.x * 256 + threadIdx.x;
    if (i < OUTC * CC) {
        const int o = i / CC, c = i - o * CC;
        const float w1 = cw[o * (2 * CC) + c];
        const float w2 = cw[o * (2 * CC) + CC + c];
        Wcat[o * CC + c]          = w1 - w2;
        Wcat[(OUTC + o) * CC + c] = w2;
    }
}

// ---------------------------------------------------------------------------
// K3b: uv[m][0:192] = norm[m]*(xn[m]·(W1-W2)^T)+b ; uv[m][192:384] = norm[m]*(xn[m]·W2^T)
// ---------------------------------------------------------------------------
__global__ __launch_bounds__(256) void k3_gemm(const float* __restrict__ xn,
                                               const float* __restrict__ Wcat,
                                               const float* __restrict__ normv,
                                               const float* __restrict__ conv_b,
                                               float* __restrict__ uv) {
    const int m0 = blockIdx.x * 64;
    const int o0 = blockIdx.y * 64;
    __shared__ __align__(16) float As[64 * 20];
    __shared__ __align__(16) float Bs[64 * 20];
    const int tid = threadIdx.x;
    const int tx  = tid & 15;
    const int ty  = tid >> 4;
    float acc[4][4] = {};

    for (int k0 = 0; k0 < CC; k0 += 16) {
        __syncthreads();
        const int row = tid >> 2;
        const int k4  = (tid & 3) << 2;
        *(float4*)&As[row * 20 + k4] = *(const float4*)&xn[(size_t)(m0 + row) * CC + k0 + k4];
        *(float4*)&Bs[row * 20 + k4] = *(const float4*)&Wcat[(size_t)(o0 + row) * CC + k0 + k4];
        __syncthreads();
#pragma unroll
        for (int kk = 0; kk < 16; kk += 4) {
            float4 av[4], bv[4];
#pragma unroll
            for (int i = 0; i < 4; ++i) av[i] = *(const float4*)&As[(i * 16 + ty) * 20 + kk];
#pragma unroll
            for (int j = 0; j < 4; ++j) bv[j] = *(const float4*)&Bs[(j * 16 + tx) * 20 + kk];
#pragma unroll
            for (int i = 0; i < 4; ++i)
#pragma unroll
                for (int j = 0; j < 4; ++j)
                    acc[i][j] += av[i].x * bv[j].x + av[i].y * bv[j].y +
                                 av[i].z * bv[j].z + av[i].w * bv[j].w;
        }
    }
    float nrm[4];
#pragma unroll
    for (int i = 0; i < 4; ++i) nrm[i] = normv[m0 + i * 16 + ty];
#pragma unroll
    for (int i = 0; i < 4; ++i)
#pragma unroll
        for (int j = 0; j < 4; ++j) {
            const int o = o0 + j * 16 + tx;
            float vvv = acc[i][j] * nrm[i];
            if (o < OUTC) vvv += conv_b[o];
            uv[(size_t)(m0 + i * 16 + ty) * (2 * OUTC) + o] = vvv;
        }
}

// ---------------------------------------------------------------------------
// K4_fused: one pass over the 9-neighbor gather:
//   amax[n][o] = u[n][o] + max_k v[idx][o],  amin = u + min_k v
//   per-block BN partials: S = sum_k (u+v), Q = sum_k (u+v)^2
// thread = (point p of 32, channel group g of 8 x 24ch). XCD-pinned: b = blk&7.
// ---------------------------------------------------------------------------
__global__ __launch_bounds__(256) void k4_fused(const float* __restrict__ uv,
                                                const int* __restrict__ idxb,
                                                float* __restrict__ amax,
                                                float* __restrict__ amin,
                                                float* __restrict__ partials) {
    const int flat = blockIdx.x;
    const int b    = flat & 7;           // round-robin -> same XCD per batch
    const int tile = flat >> 3;
    const int tid  = threadIdx.x;
    const int p    = tid >> 3;           // 0..31
    const int g    = tid & 7;            // 0..7 (24 channels each)
    const int n    = tile * 32 + p;
    const size_t base = (size_t)b * NPTS;
    __shared__ float red[256 * 25];

    float sv[24], sv2[24], vmx[24], vmn[24];
#pragma unroll
    for (int c = 0; c < 24; ++c) { sv[c] = 0.f; sv2[c] = 0.f; vmx[c] = -3.4e38f; vmn[c] = 3.4e38f; }

    const int* ix = &idxb[(base + n) * KNN];
#pragma unroll
    for (int k = 0; k < KNN; ++k) {
        const int m = ix[k];
        const float* vr = &uv[(base + m) * (2 * OUTC) + OUTC + g * 24];
#pragma unroll
        for (int c4 = 0; c4 < 6; ++c4) {
            const float4 v = *(const float4*)&vr[c4 * 4];
            const int c = c4 * 4;
            sv[c+0] += v.x; sv2[c+0] += v.x*v.x; vmx[c+0] = fmaxf(vmx[c+0], v.x); vmn[c+0] = fminf(vmn[c+0], v.x);
            sv[c+1] += v.y; sv2[c+1] += v.y*v.y; vmx[c+1] = fmaxf(vmx[c+1], v.y); vmn[c+1] = fminf(vmn[c+1], v.y);
            sv[c+2] += v.z; sv2[c+2] += v.z*v.z; vmx[c+2] = fmaxf(vmx[c+2], v.z); vmn[c+2] = fminf(vmn[c+2], v.z);
            sv[c+3] += v.w; sv2[c+3] += v.w*v.w; vmx[c+3] = fmaxf(vmx[c+3], v.w); vmn[c+3] = fminf(vmn[c+3], v.w);
        }
    }
    const float* ur = &uv[(base + n) * (2 * OUTC) + g * 24];
    float S[24], Q[24];
    float* am = &amax[(base + n) * OUTC + g * 24];
    float* an = &amin[(base + n) * OUTC + g * 24];
#pragma unroll
    for (int c4 = 0; c4 < 6; ++c4) {
        const float4 u4 = *(const float4*)&ur[c4 * 4];
        const int c = c4 * 4;
        float4 mx, mn;
        mx.x = u4.x + vmx[c+0]; mn.x = u4.x + vmn[c+0];
        mx.y = u4.y + vmx[c+1]; mn.y = u4.y + vmn[c+1];
        mx.z = u4.z + vmx[c+2]; mn.z = u4.z + vmn[c+2];
        mx.w = u4.w + vmx[c+3]; mn.w = u4.w + vmn[c+3];
        *(float4*)&am[c4 * 4] = mx;
        *(float4*)&an[c4 * 4] = mn;
        S[c+0] = 9.f*u4.x + sv[c+0];  Q[c+0] = u4.x*(9.f*u4.x + 2.f*sv[c+0]) + sv2[c+0];
        S[c+1] = 9.f*u4.y + sv[c+1];  Q[c+1] = u4.y*(9.f*u4.y + 2.f*sv[c+1]) + sv2[c+1];
        S[c+2] = 9.f*u4.z + sv[c+2];  Q[c+2] = u4.z*(9.f*u4.z + 2.f*sv[c+2]) + sv2[c+2];
        S[c+3] = 9.f*u4.w + sv[c+3];  Q[c+3] = u4.w*(9.f*u4.w + 2.f*sv[c+3]) + sv2[c+3];
    }
    // deterministic block reduce over 32 points
#pragma unroll
    for (int c = 0; c < 24; ++c) red[tid * 25 + c] = S[c];
    __syncthreads();
    float accS = 0.f;
    if (tid < OUTC) {
        const int go = tid / 24, co = tid - go * 24;
        for (int pp = 0; pp < 32; ++pp) accS += red[(pp * 8 + go) * 25 + co];
    }
    __syncthreads();
#pragma unroll
    for (int c = 0; c < 24; ++c) red[tid * 25 + c] = Q[c];
    __syncthreads();
    if (tid < OUTC) {
        const int go = tid / 24, co = tid - go * 24;
        float accQ = 0.f;
        for (int pp = 0; pp < 32; ++pp) accQ += red[(pp * 8 + go) * 25 + co];
        partials[(size_t)flat * (2 * OUTC) + tid]        = accS;
        partials[(size_t)flat * (2 * OUTC) + OUTC + tid] = accQ;
    }
}

// ---------------------------------------------------------------------------
// K4b: reduce partials deterministically -> scale/shift per channel
// ---------------------------------------------------------------------------
__global__ __launch_bounds__(192) void k4b_finalize(const float* __restrict__ partials,
                                                    const float* __restrict__ gamma,
                                                    const float* __restrict__ beta,
                                                    float* __restrict__ scsh) {
    const int o = threadIdx.x;
    float S = 0.f, Q = 0.f;
    for (int blk = 0; blk < NBLK4; ++blk) {
        S += partials[(size_t)blk * (2 * OUTC) + o];
        Q += partials[(size_t)blk * (2 * OUTC) + OUTC + o];
    }
    const float cnt  = (float)BB * (float)NPTS * (float)KNN;
    const float mean = S / cnt;
    float var = Q / cnt - mean * mean;
    var = fmaxf(var, 0.0f);
    const float scale = gamma[o] * rsqrtf(var + 1e-5f);
    scsh[o]        = scale;
    scsh[OUTC + o] = beta[o] - mean * scale;
}

// ---------------------------------------------------------------------------
// K5: out[b][o][n] = max(gelu(amax*sc+sh), gelu(amin*sc+sh))  (gelu unimodal)
// ---------------------------------------------------------------------------
__global__ __launch_bounds__(256) void k5_out(const float* __restrict__ amax,
                                              const float* __restrict__ amin,
                                              const float* __restrict__ scsh,
                                              float* __restrict__ out) {
    const int b  = blockIdx.y;
    const int n0 = blockIdx.x * 64;
    __shared__ float zb[64 * 193];
    __shared__ float ssc[OUTC];
    __shared__ float ssh[OUTC];
    const int tid = threadIdx.x;
    for (int q = tid; q < OUTC; q += 256) {
        ssc[q] = scsh[q];
        ssh[q] = scsh[OUTC + q];
    }
    __syncthreads();
    const int p  = tid >> 2;
    const int og = tid & 3;
    const int n  = n0 + p;
    const size_t rb = ((size_t)b * NPTS + n) * OUTC + og * 48;
#pragma unroll
    for (int t4 = 0; t4 < 12; ++t4) {
        const float4 ax = *(const float4*)&amax[rb + t4 * 4];
        const float4 an = *(const float4*)&amin[rb + t4 * 4];
        const int ob = og * 48 + t4 * 4;
        float z1, z2;
        z1 = ax.x * ssc[ob+0] + ssh[ob+0]; z2 = an.x * ssc[ob+0] + ssh[ob+0];
        zb[p * 193 + ob + 0] = fmaxf(gelu_f(z1), gelu_f(z2));
        z1 = ax.y * ssc[ob+1] + ssh[ob+1]; z2 = an.y * ssc[ob+1] + ssh[ob+1];
        zb[p * 193 + ob + 1] = fmaxf(gelu_f(z1), gelu_f(z2));
        z1 = ax.z * ssc[ob+2] + ssh[ob+2]; z2 = an.z * ssc[ob+2] + ssh[ob+2];
        zb[p * 193 + ob + 2] = fmaxf(gelu_f(z1), gelu_f(z2));
        z1 = ax.w * ssc[ob+3] + ssh[ob+3]; z2 = an.w * ssc[ob+3] + ssh[ob+3];
        zb[p * 193 + ob + 3] = fmaxf(gelu_f(z1), gelu_f(z2));
    }
    __syncthreads();
    float* ob2 = out + (size_t)b * OUTC * NPTS;
    for (int q = tid; q < 64 * OUTC; q += 256) {
        const int o  = q >> 6;
        const int pp = q & 63;
        ob2[(size_t)o * NPTS + n0 + pp] = zb[pp * 193 + o];
    }
}

// ---------------------------------------------------------------------------
extern "C" void kernel_launch(void* const* d_in, const int* in_sizes, int n_in,
                              void* d_out, int out_size, void* d_ws, size_t ws_size,
                              hipStream_t stream) {
    const float* x        = (const float*)d_in[0];
    const float* conv_w   = (const float*)d_in[1];
    const float* conv_b   = (const float*)d_in[2];
    const float* bn_gamma = (const float*)d_in[3];
    const float* bn_beta  = (const float*)d_in[4];
    float* out = (float*)d_out;

    // workspace layout (floats)
    float* ws = (float*)d_ws;
    const size_t SZ_XN = (size_t)BB * NPTS * CC;     // 4,816,896 f
    const size_t SZ_NV = (size_t)BB * NPTS;          // 25,088 f
    const size_t SZ_A  = (size_t)BB * NPTS * OUTC;   // 4,816,896 f

    int*   idxb     = (int*)ws;                                   // 225,792 ints
    float* Wcat     = (float*)(idxb + (size_t)BB * NPTS * KNN);   // 73,728 f
    float* uv       = Wcat + (size_t)(2 * OUTC) * CC;             // 9,633,792 f
    float* partials = uv + (size_t)BB * NPTS * (2 * OUTC);        // NBLK4*384 f
    float* scsh     = partials + (size_t)NBLK4 * (2 * OUTC);      // 384 f
    float* normv    = scsh + 2 * OUTC;                            // 25,088 f
    float* sqv      = normv + SZ_NV;                              // 25,088 f
    float* xn       = sqv + SZ_NV;                                // 4,816,896 f
    unsigned short* xh = (unsigned short*)(xn + SZ_XN);           // 4,816,896 u16
    unsigned short* xl = xh + SZ_XN;                              // 4,816,896 u16
    // aliases (non-overlapping lifetimes):
    unsigned long long* pd = (unsigned long long*)uv;    // k2->k2b, dead before k3 writes uv
    float* amax = xn;                                    // k4 writes after k3's last xn read
    float* amin = xn + SZ_A;                             // spans dead xh/xl exactly

    k1_normalize<<<dim3(NTILES, BB), 256, 0, stream>>>(x, xn, xh, xl, normv, sqv);
    k2_knn<<<dim3(NTILES, NCH, BB), 256, 0, stream>>>(xh, xl, sqv, pd);
    k2b_merge<<<dim3(NTILES, BB), 256, 0, stream>>>(xn, pd, idxb);
    k3a_wcat<<<(OUTC * CC + 255) / 256, 256, 0, stream>>>(conv_w, Wcat);
    k3_gemm<<<dim3(BB * NPTS / 64, (2 * OUTC) / 64), 256, 0, stream>>>(xn, Wcat, normv, conv_b, uv);
    k4_fused<<<NBLK4, 256, 0, stream>>>(uv, idxb, amax, amin, partials);
    k4b_finalize<<<1, 192, 0, stream>>>(partials, bn_gamma, bn_beta, scsh);
    k5_out<<<dim3(NTILES, BB), 256, 0, stream>>>(amax, amin, scsh, out);
}

// Round 5
// 484.067 us; speedup vs baseline: 8.2776x; 1.6387x over previous
//
#include <hip/hip_runtime.h>
#include <hip/hip_bf16.h>
#include <math.h>

// Problem constants
#define BB 8
#define CC 192
#define HH 56
#define WW 56
#define NPTS 3136        // H*W
#define OUTC 192
#define KNN 9
#define NTILES 49        // NPTS/64
#define NCH 2            // k2 column chunks
#define NT4 98           // NPTS/32 (k4 tiles)
#define NBLK4 (NT4 * BB) // 784

typedef __bf16 bf16x8 __attribute__((ext_vector_type(8)));
typedef float  f32x16 __attribute__((ext_vector_type(16)));

__device__ __forceinline__ unsigned short f2bf(float f) {
    unsigned u = __float_as_uint(f);
    u += 0x7fffu + ((u >> 16) & 1u);       // RNE
    return (unsigned short)(u >> 16);
}
__device__ __forceinline__ float bf2f(unsigned short h) {
    return __uint_as_float(((unsigned)h) << 16);
}
__device__ __forceinline__ float gelu_f(float z) {
    return 0.5f * z * (1.0f + erff(z * 0.70710678118654752f));
}

// sorted-ascending top-12 insert, u32 keys (dist-high-bits<<9 | tag)
__device__ __forceinline__ void ins12u32(unsigned (&t)[12], unsigned key) {
    if (key >= t[11]) return;
    t[11] = key;
#pragma unroll
    for (int q = 11; q > 0; --q) {
        const unsigned a = t[q-1], bq = t[q];
        const bool sw = bq < a;
        t[q-1] = sw ? bq : a;
        t[q]   = sw ? a : bq;
    }
}

// sorted-ascending top-12 insert, u64 keys
__device__ __forceinline__ void ins12u(unsigned long long (&t)[12], unsigned long long key) {
    if (key >= t[11]) return;
    t[11] = key;
#pragma unroll
    for (int q = 11; q > 0; --q) {
        const unsigned long long a = t[q-1], bq = t[q];
        const bool sw = bq < a;
        t[q-1] = sw ? bq : a;
        t[q]   = sw ? a : bq;
    }
}

__device__ __forceinline__ void ins9d(double (&d)[9], int (&ix)[9], double nd, int ni) {
    if (!((nd < d[8]) || (nd == d[8] && ni < ix[8]))) return;
    d[8] = nd; ix[8] = ni;
#pragma unroll
    for (int q = 8; q > 0; --q) {
        if ((d[q] < d[q-1]) || (d[q] == d[q-1] && ix[q] < ix[q-1])) {
            double t = d[q]; d[q] = d[q-1]; d[q-1] = t;
            int t2 = ix[q]; ix[q] = ix[q-1]; ix[q-1] = t2;
        }
    }
}

// ---------------------------------------------------------------------------
// K1: transpose (B,C,N)->(B,N,C), L2-normalize rows; emit xn (f32),
//     xh/xl (bf16 hi/lo split of xn), norm
// ---------------------------------------------------------------------------
__global__ __launch_bounds__(256) void k1_normalize(const float* __restrict__ x,
                                                    float* __restrict__ xn,
                                                    unsigned short* __restrict__ xh,
                                                    unsigned short* __restrict__ xl,
                                                    float* __restrict__ normv) {
    const int b  = blockIdx.y;
    const int n0 = blockIdx.x * 64;
    __shared__ float tile[64 * 193];
    __shared__ float red[4][64];
    __shared__ float inv[64];
    const int tid = threadIdx.x;
    const int p   = tid & 63;
    const int cg  = tid >> 6;
    const float* xb = x + (size_t)b * CC * NPTS;

    float acc = 0.f;
#pragma unroll 4
    for (int t = 0; t < 48; ++t) {
        const int c = cg * 48 + t;
        const float v = xb[(size_t)c * NPTS + n0 + p];
        tile[p * 193 + c] = v;
        acc += v * v;
    }
    red[cg][p] = acc;
    __syncthreads();
    if (cg == 0) {
        const float s  = red[0][p] + red[1][p] + red[2][p] + red[3][p];
        float nc = sqrtf(s);
        nc = fmaxf(nc, 1e-12f);
        normv[b * NPTS + n0 + p] = nc;
        inv[p] = 1.0f / nc;
    }
    __syncthreads();
    const size_t base = ((size_t)b * NPTS + n0) * CC;
    float* dst = xn + base;
    for (int q = tid; q < 64 * CC / 4; q += 256) {
        const int f   = q * 4;
        const int row = f / CC;
        const int c   = f - row * CC;
        const float iv = inv[row];
        float4 v;
        v.x = tile[row * 193 + c + 0] * iv;
        v.y = tile[row * 193 + c + 1] * iv;
        v.z = tile[row * 193 + c + 2] * iv;
        v.w = tile[row * 193 + c + 3] * iv;
        *(float4*)&dst[f] = v;
        ushort4 hv, lv;
        hv.x = f2bf(v.x); lv.x = f2bf(v.x - bf2f(hv.x));
        hv.y = f2bf(v.y); lv.y = f2bf(v.y - bf2f(hv.y));
        hv.z = f2bf(v.z); lv.z = f2bf(v.z - bf2f(hv.z));
        hv.w = f2bf(v.w); lv.w = f2bf(v.w - bf2f(hv.w));
        *(ushort4*)&xh[base + f] = hv;
        *(ushort4*)&xl[base + f] = lv;
    }
}

// ---------------------------------------------------------------------------
// K2: transposed-MFMA cosine-KNN. Stationary row-point frags in regs (hi+lo);
// col-points streamed through ONE LDS plane (hi pass, then lo pass).
// Output lane-axis = row-point, so each lane scans its own row's 16 candidates
// in registers with u32 keys (quantized 1-dot | 9-bit tag). No dist tile.
// grid (49 row-tiles, 2 chunks, 8 batches), block 256, 3 blocks/CU.
// ---------------------------------------------------------------------------
__global__ __launch_bounds__(256, 3) void k2_knn(const unsigned short* __restrict__ xh,
                                                 const unsigned short* __restrict__ xl,
                                                 unsigned long long* __restrict__ pd) {
    const int b     = blockIdx.z;
    const int chunk = blockIdx.y;
    const int r0    = blockIdx.x * 64;
    const int t0    = chunk ? 25 : 0;
    const int t1    = chunk ? 49 : 25;

    __shared__ __align__(16) unsigned short Cs[64 * 200];   // 25600 B, one plane
    __shared__ unsigned long long cdu[4][64][12];           // 24576 B merge buffer

    const int tid  = threadIdx.x;
    const int w    = tid >> 6;
    const int lane = tid & 63;
    const int wc   = w & 1;          // row half
    const int wr   = w >> 1;         // col half
    const int l31  = lane & 31;
    const int lhi  = lane >> 5;
    const int koffe = lhi * 8;
    const int myrow = wc * 32 + l31;

    // stationary row-point fragments (hi+lo) — ~96 VGPRs
    const size_t rbase = ((size_t)b * NPTS + (r0 + myrow)) * CC;
    bf16x8 Rh[12], Rl[12];
#pragma unroll
    for (int c = 0; c < 12; ++c) {
        Rh[c] = *(const bf16x8*)(const void*)(xh + rbase + c * 16 + koffe);
        Rl[c] = *(const bf16x8*)(const void*)(xl + rbase + c * 16 + koffe);
    }

    unsigned t12[12];
#pragma unroll
    for (int q = 0; q < 12; ++q) t12[q] = 0xFFFFFFFFu;

    const int cfb = (wr * 32 + l31) * 200 + koffe;

    for (int ct = t0; ct < t1; ++ct) {
        const int c0 = ct * 64;
        __syncthreads();   // prev tile's lo-pass frag reads done before overwrite
        // stage hi plane (64 points x 192ch, 1536 16B chunks, 6/thread)
#pragma unroll
        for (int rep = 0; rep < 6; ++rep) {
            const int cidx  = rep * 256 + tid;
            const int point = cidx / 24;
            const int c8    = cidx - point * 24;
            *(uint4*)(void*)&Cs[point * 200 + c8 * 8] =
                *(const uint4*)(const void*)(xh + ((size_t)b * NPTS + c0 + point) * CC + c8 * 8);
        }
        __syncthreads();

        f32x16 acc;
#pragma unroll
        for (int r = 0; r < 16; ++r) acc[r] = 0.f;

        // pass 1+2: C_hi·R_hi + C_hi·R_lo   (note operand order: cols first ->
        // output col(lane axis) = row-point, regs = col-points)
#pragma unroll
        for (int c = 0; c < 12; ++c) {
            const bf16x8 cf = *(const bf16x8*)(const void*)&Cs[cfb + c * 16];
            acc = __builtin_amdgcn_mfma_f32_32x32x16_bf16(cf, Rh[c], acc, 0, 0, 0);
            acc = __builtin_amdgcn_mfma_f32_32x32x16_bf16(cf, Rl[c], acc, 0, 0, 0);
        }
        __syncthreads();   // hi-plane reads done
        // stage lo plane
#pragma unroll
        for (int rep = 0; rep < 6; ++rep) {
            const int cidx  = rep * 256 + tid;
            const int point = cidx / 24;
            const int c8    = cidx - point * 24;
            *(uint4*)(void*)&Cs[point * 200 + c8 * 8] =
                *(const uint4*)(const void*)(xl + ((size_t)b * NPTS + c0 + point) * CC + c8 * 8);
        }
        __syncthreads();
        // pass 3: C_lo·R_hi
#pragma unroll
        for (int c = 0; c < 12; ++c) {
            const bf16x8 cf = *(const bf16x8*)(const void*)&Cs[cfb + c * 16];
            acc = __builtin_amdgcn_mfma_f32_32x32x16_bf16(cf, Rh[c], acc, 0, 0, 0);
        }

        // scan 16 candidates (this lane's row, cols mapped by reg) in registers
        const unsigned tbase = (unsigned)((ct - t0) << 4);
#pragma unroll
        for (int reg = 0; reg < 16; ++reg) {
            const float d = fmaxf(1.0f - acc[reg], 0.0f);
            const unsigned key = (__float_as_uint(d) & 0xFFFFFE00u) | (tbase | (unsigned)reg);
            ins12u32(t12, key);
        }
    }

    // dump per-lane list with col reconstruction: u64 = key<<32 | col
#pragma unroll
    for (int q = 0; q < 12; ++q) {
        const unsigned key = t12[q];
        const int tag = (int)(key & 511u);
        const int reg = tag & 15;
        const int col = (t0 + (tag >> 4)) * 64 + wr * 32 + ((reg & 3) + 8 * (reg >> 2) + 4 * lhi);
        cdu[wr * 2 + lhi][myrow][q] = ((unsigned long long)key << 32) | (unsigned)col;
    }
    __syncthreads();
    // merge 4 lists per row -> top-12, write to pd
    if (tid < 64) {
        unsigned long long t[12];
#pragma unroll
        for (int q = 0; q < 12; ++q) t[q] = cdu[0][tid][q];
        for (int s = 1; s < 4; ++s)
#pragma unroll
            for (int q = 0; q < 12; ++q) ins12u(t, cdu[s][tid][q]);
        const size_t gbase = ((size_t)b * NPTS + r0 + tid) * (NCH * 12) + chunk * 12;
#pragma unroll
        for (int q = 0; q < 12; ++q) pd[gbase + q] = t[q];
    }
}

// ---------------------------------------------------------------------------
// K2b: merge chunk lists -> top-12, fp64 re-rank -> idx[b,n,9]
// ---------------------------------------------------------------------------
__global__ __launch_bounds__(256) void k2b_merge(const float* __restrict__ xn,
                                                 const unsigned long long* __restrict__ pd,
                                                 int* __restrict__ idxout) {
    const int b  = blockIdx.y;
    const int r0 = blockIdx.x * 64;
    __shared__ int    ci[64][12];
    __shared__ double dd[64][13];
    const int tid = threadIdx.x;
    if (tid < 64) {
        const size_t base = ((size_t)b * NPTS + r0 + tid) * (NCH * 12);
        unsigned long long t[12];
#pragma unroll
        for (int q = 0; q < 12; ++q) t[q] = pd[base + q];
#pragma unroll
        for (int q = 0; q < 12; ++q) ins12u(t, pd[base + 12 + q]);
#pragma unroll
        for (int q = 0; q < 12; ++q) ci[tid][q] = (int)(t[q] & 0xFFFFFFFFull);
    }
    __syncthreads();
    const float* xb = xn + (size_t)b * NPTS * CC;
    {
        const int p = tid >> 2;
        const int s = tid & 3;
        const float* xr = xb + (size_t)(r0 + p) * CC;
#pragma unroll
        for (int t3 = 0; t3 < 3; ++t3) {
            const int cs2 = s + t3 * 4;
            const int m   = ci[p][cs2];
            const float* xm = xb + (size_t)m * CC;
            double dot = 0.0, sqm = 0.0, sqn = 0.0;
            for (int c = 0; c < CC; ++c) {
                const double a  = (double)xr[c];
                const double b2 = (double)xm[c];
                dot += a * b2;
                sqm += b2 * b2;
                sqn += a * a;
            }
            dd[p][cs2] = sqn + sqm - 2.0 * dot;
        }
    }
    __syncthreads();
    if (tid < 64) {
        double fd[9]; int fi[9];
#pragma unroll
        for (int q = 0; q < 9; ++q) { fd[q] = 1e300; fi[q] = 0x7fffffff; }
#pragma unroll
        for (int cs2 = 0; cs2 < 12; ++cs2)
            ins9d(fd, fi, dd[tid][cs2], ci[tid][cs2]);
#pragma unroll
        for (int q = 0; q < 9; ++q)
            idxout[((size_t)b * NPTS + r0 + tid) * KNN + q] = fi[q];
    }
}

// ---------------------------------------------------------------------------
// K3a: Wcat[0:192][c] = W1 - W2 ; Wcat[192:384][c] = W2
// ---------------------------------------------------------------------------
__global__ __launch_bounds__(256) void k3a_wcat(const float* __restrict__ cw,
                                                float* __restrict__ Wcat) {
    const int i = blockIdx.x * 256 + threadIdx.x;
    if (i < OUTC * CC) {
        const int o = i / CC, c = i - o * CC;
        const float w1 = cw[o * (2 * CC) + c];
        const float w2 = cw[o * (2 * CC) + CC + c];
        Wcat[o * CC + c]          = w1 - w2;
        Wcat[(OUTC + o) * CC + c] = w2;
    }
}

// ---------------------------------------------------------------------------
// K3b: uv[m][0:192] = norm[m]*(xn[m]·(W1-W2)^T)+b ; uv[m][192:384] = norm[m]*(xn[m]·W2^T)
// ---------------------------------------------------------------------------
__global__ __launch_bounds__(256) void k3_gemm(const float* __restrict__ xn,
                                               const float* __restrict__ Wcat,
                                               const float* __restrict__ normv,
                                               const float* __restrict__ conv_b,
                                               float* __restrict__ uv) {
    const int m0 = blockIdx.x * 64;
    const int o0 = blockIdx.y * 64;
    __shared__ __align__(16) float As[64 * 20];
    __shared__ __align__(16) float Bs[64 * 20];
    const int tid = threadIdx.x;
    const int tx  = tid & 15;
    const int ty  = tid >> 4;
    float acc[4][4] = {};

    for (int k0 = 0; k0 < CC; k0 += 16) {
        __syncthreads();
        const int row = tid >> 2;
        const int k4  = (tid & 3) << 2;
        *(float4*)&As[row * 20 + k4] = *(const float4*)&xn[(size_t)(m0 + row) * CC + k0 + k4];
        *(float4*)&Bs[row * 20 + k4] = *(const float4*)&Wcat[(size_t)(o0 + row) * CC + k0 + k4];
        __syncthreads();
#pragma unroll
        for (int kk = 0; kk < 16; kk += 4) {
            float4 av[4], bv[4];
#pragma unroll
            for (int i = 0; i < 4; ++i) av[i] = *(const float4*)&As[(i * 16 + ty) * 20 + kk];
#pragma unroll
            for (int j = 0; j < 4; ++j) bv[j] = *(const float4*)&Bs[(j * 16 + tx) * 20 + kk];
#pragma unroll
            for (int i = 0; i < 4; ++i)
#pragma unroll
                for (int j = 0; j < 4; ++j)
                    acc[i][j] += av[i].x * bv[j].x + av[i].y * bv[j].y +
                                 av[i].z * bv[j].z + av[i].w * bv[j].w;
        }
    }
    float nrm[4];
#pragma unroll
    for (int i = 0; i < 4; ++i) nrm[i] = normv[m0 + i * 16 + ty];
#pragma unroll
    for (int i = 0; i < 4; ++i)
#pragma unroll
        for (int j = 0; j < 4; ++j) {
            const int o = o0 + j * 16 + tx;
            float vvv = acc[i][j] * nrm[i];
            if (o < OUTC) vvv += conv_b[o];
            uv[(size_t)(m0 + i * 16 + ty) * (2 * OUTC) + o] = vvv;
        }
}

// ---------------------------------------------------------------------------
// K4_fused: one pass over the 9-neighbor gather:
//   amax[n][o] = u[n][o] + max_k v[idx][o],  amin = u + min_k v
//   per-block BN partials: S = sum_k (u+v), Q = sum_k (u+v)^2
// ---------------------------------------------------------------------------
__global__ __launch_bounds__(256) void k4_fused(const float* __restrict__ uv,
                                                const int* __restrict__ idxb,
                                                float* __restrict__ amax,
                                                float* __restrict__ amin,
                                                float* __restrict__ partials) {
    const int flat = blockIdx.x;
    const int b    = flat & 7;           // round-robin -> same XCD per batch
    const int tile = flat >> 3;
    const int tid  = threadIdx.x;
    const int p    = tid >> 3;           // 0..31
    const int g    = tid & 7;            // 0..7 (24 channels each)
    const int n    = tile * 32 + p;
    const size_t base = (size_t)b * NPTS;
    __shared__ float red[256 * 25];

    float sv[24], sv2[24], vmx[24], vmn[24];
#pragma unroll
    for (int c = 0; c < 24; ++c) { sv[c] = 0.f; sv2[c] = 0.f; vmx[c] = -3.4e38f; vmn[c] = 3.4e38f; }

    const int* ix = &idxb[(base + n) * KNN];
#pragma unroll
    for (int k = 0; k < KNN; ++k) {
        const int m = ix[k];
        const float* vr = &uv[(base + m) * (2 * OUTC) + OUTC + g * 24];
#pragma unroll
        for (int c4 = 0; c4 < 6; ++c4) {
            const float4 v = *(const float4*)&vr[c4 * 4];
            const int c = c4 * 4;
            sv[c+0] += v.x; sv2[c+0] += v.x*v.x; vmx[c+0] = fmaxf(vmx[c+0], v.x); vmn[c+0] = fminf(vmn[c+0], v.x);
            sv[c+1] += v.y; sv2[c+1] += v.y*v.y; vmx[c+1] = fmaxf(vmx[c+1], v.y); vmn[c+1] = fminf(vmn[c+1], v.y);
            sv[c+2] += v.z; sv2[c+2] += v.z*v.z; vmx[c+2] = fmaxf(vmx[c+2], v.z); vmn[c+2] = fminf(vmn[c+2], v.z);
            sv[c+3] += v.w; sv2[c+3] += v.w*v.w; vmx[c+3] = fmaxf(vmx[c+3], v.w); vmn[c+3] = fminf(vmn[c+3], v.w);
        }
    }
    const float* ur = &uv[(base + n) * (2 * OUTC) + g * 24];
    float S[24], Q[24];
    float* am = &amax[(base + n) * OUTC + g * 24];
    float* an = &amin[(base + n) * OUTC + g * 24];
#pragma unroll
    for (int c4 = 0; c4 < 6; ++c4) {
        const float4 u4 = *(const float4*)&ur[c4 * 4];
        const int c = c4 * 4;
        float4 mx, mn;
        mx.x = u4.x + vmx[c+0]; mn.x = u4.x + vmn[c+0];
        mx.y = u4.y + vmx[c+1]; mn.y = u4.y + vmn[c+1];
        mx.z = u4.z + vmx[c+2]; mn.z = u4.z + vmn[c+2];
        mx.w = u4.w + vmx[c+3]; mn.w = u4.w + vmn[c+3];
        *(float4*)&am[c4 * 4] = mx;
        *(float4*)&an[c4 * 4] = mn;
        S[c+0] = 9.f*u4.x + sv[c+0];  Q[c+0] = u4.x*(9.f*u4.x + 2.f*sv[c+0]) + sv2[c+0];
        S[c+1] = 9.f*u4.y + sv[c+1];  Q[c+1] = u4.y*(9.f*u4.y + 2.f*sv[c+1]) + sv2[c+1];
        S[c+2] = 9.f*u4.z + sv[c+2];  Q[c+2] = u4.z*(9.f*u4.z + 2.f*sv[c+2]) + sv2[c+2];
        S[c+3] = 9.f*u4.w + sv[c+3];  Q[c+3] = u4.w*(9.f*u4.w + 2.f*sv[c+3]) + sv2[c+3];
    }
    // deterministic block reduce over 32 points
#pragma unroll
    for (int c = 0; c < 24; ++c) red[tid * 25 + c] = S[c];
    __syncthreads();
    float accS = 0.f;
    if (tid < OUTC) {
        const int go = tid / 24, co = tid - go * 24;
        for (int pp = 0; pp < 32; ++pp) accS += red[(pp * 8 + go) * 25 + co];
    }
    __syncthreads();
#pragma unroll
    for (int c = 0; c < 24; ++c) red[tid * 25 + c] = Q[c];
    __syncthreads();
    if (tid < OUTC) {
        const int go = tid / 24, co = tid - go * 24;
        float accQ = 0.f;
        for (int pp = 0; pp < 32; ++pp) accQ += red[(pp * 8 + go) * 25 + co];
        partials[(size_t)flat * (2 * OUTC) + tid]        = accS;
        partials[(size_t)flat * (2 * OUTC) + OUTC + tid] = accQ;
    }
}

// ---------------------------------------------------------------------------
// K4b: reduce partials deterministically -> scale/shift per channel
// ---------------------------------------------------------------------------
__global__ __launch_bounds__(192) void k4b_finalize(const float* __restrict__ partials,
                                                    const float* __restrict__ gamma,
                                                    const float* __restrict__ beta,
                                                    float* __restrict__ scsh) {
    const int o = threadIdx.x;
    float S = 0.f, Q = 0.f;
    for (int blk = 0; blk < NBLK4; ++blk) {
        S += partials[(size_t)blk * (2 * OUTC) + o];
        Q += partials[(size_t)blk * (2 * OUTC) + OUTC + o];
    }
    const float cnt  = (float)BB * (float)NPTS * (float)KNN;
    const float mean = S / cnt;
    float var = Q / cnt - mean * mean;
    var = fmaxf(var, 0.0f);
    const float scale = gamma[o] * rsqrtf(var + 1e-5f);
    scsh[o]        = scale;
    scsh[OUTC + o] = beta[o] - mean * scale;
}

// ---------------------------------------------------------------------------
// K5: out[b][o][n] = max(gelu(amax*sc+sh), gelu(amin*sc+sh))  (gelu unimodal)
// ---------------------------------------------------------------------------
__global__ __launch_bounds__(256) void k5_out(const float* __restrict__ amax,
                                              const float* __restrict__ amin,
                                              const float* __restrict__ scsh,
                                              float* __restrict__ out) {
    const int b  = blockIdx.y;
    const int n0 = blockIdx.x * 64;
    __shared__ float zb[64 * 193];
    __shared__ float ssc[OUTC];
    __shared__ float ssh[OUTC];
    const int tid = threadIdx.x;
    for (int q = tid; q < OUTC; q += 256) {
        ssc[q] = scsh[q];
        ssh[q] = scsh[OUTC + q];
    }
    __syncthreads();
    const int p  = tid >> 2;
    const int og = tid & 3;
    const int n  = n0 + p;
    const size_t rb = ((size_t)b * NPTS + n) * OUTC + og * 48;
#pragma unroll
    for (int t4 = 0; t4 < 12; ++t4) {
        const float4 ax = *(const float4*)&amax[rb + t4 * 4];
        const float4 an = *(const float4*)&amin[rb + t4 * 4];
        const int ob = og * 48 + t4 * 4;
        float z1, z2;
        z1 = ax.x * ssc[ob+0] + ssh[ob+0]; z2 = an.x * ssc[ob+0] + ssh[ob+0];
        zb[p * 193 + ob + 0] = fmaxf(gelu_f(z1), gelu_f(z2));
        z1 = ax.y * ssc[ob+1] + ssh[ob+1]; z2 = an.y * ssc[ob+1] + ssh[ob+1];
        zb[p * 193 + ob + 1] = fmaxf(gelu_f(z1), gelu_f(z2));
        z1 = ax.z * ssc[ob+2] + ssh[ob+2]; z2 = an.z * ssc[ob+2] + ssh[ob+2];
        zb[p * 193 + ob + 2] = fmaxf(gelu_f(z1), gelu_f(z2));
        z1 = ax.w * ssc[ob+3] + ssh[ob+3]; z2 = an.w * ssc[ob+3] + ssh[ob+3];
        zb[p * 193 + ob + 3] = fmaxf(gelu_f(z1), gelu_f(z2));
    }
    __syncthreads();
    float* ob2 = out + (size_t)b * OUTC * NPTS;
    for (int q = tid; q < 64 * OUTC; q += 256) {
        const int o  = q >> 6;
        const int pp = q & 63;
        ob2[(size_t)o * NPTS + n0 + pp] = zb[pp * 193 + o];
    }
}

// ---------------------------------------------------------------------------
extern "C" void kernel_launch(void* const* d_in, const int* in_sizes, int n_in,
                              void* d_out, int out_size, void* d_ws, size_t ws_size,
                              hipStream_t stream) {
    const float* x        = (const float*)d_in[0];
    const float* conv_w   = (const float*)d_in[1];
    const float* conv_b   = (const float*)d_in[2];
    const float* bn_gamma = (const float*)d_in[3];
    const float* bn_beta  = (const float*)d_in[4];
    float* out = (float*)d_out;

    // workspace layout (floats)
    float* ws = (float*)d_ws;
    const size_t SZ_XN = (size_t)BB * NPTS * CC;     // 4,816,896 f
    const size_t SZ_NV = (size_t)BB * NPTS;          // 25,088 f
    const size_t SZ_A  = (size_t)BB * NPTS * OUTC;   // 4,816,896 f

    int*   idxb     = (int*)ws;                                   // 225,792 ints
    float* Wcat     = (float*)(idxb + (size_t)BB * NPTS * KNN);   // 73,728 f
    float* uv       = Wcat + (size_t)(2 * OUTC) * CC;             // 9,633,792 f
    float* partials = uv + (size_t)BB * NPTS * (2 * OUTC);        // NBLK4*384 f
    float* scsh     = partials + (size_t)NBLK4 * (2 * OUTC);      // 384 f
    float* normv    = scsh + 2 * OUTC;                            // 25,088 f
    float* xn       = normv + SZ_NV;                              // 4,816,896 f
    unsigned short* xh = (unsigned short*)(xn + SZ_XN);           // 4,816,896 u16
    unsigned short* xl = xh + SZ_XN;                              // 4,816,896 u16
    // aliases (non-overlapping lifetimes):
    unsigned long long* pd = (unsigned long long*)uv;    // k2->k2b, dead before k3 writes uv
    float* amax = xn;                                    // k4 writes after k3's last xn read
    float* amin = xn + SZ_A;                             // spans dead xh/xl region

    k1_normalize<<<dim3(NTILES, BB), 256, 0, stream>>>(x, xn, xh, xl, normv);
    k2_knn<<<dim3(NTILES, NCH, BB), 256, 0, stream>>>(xh, xl, pd);
    k2b_merge<<<dim3(NTILES, BB), 256, 0, stream>>>(xn, pd, idxb);
    k3a_wcat<<<(OUTC * CC + 255) / 256, 256, 0, stream>>>(conv_w, Wcat);
    k3_gemm<<<dim3(BB * NPTS / 64, (2 * OUTC) / 64), 256, 0, stream>>>(xn, Wcat, normv, conv_b, uv);
    k4_fused<<<NBLK4, 256, 0, stream>>>(uv, idxb, amax, amin, partials);
    k4b_finalize<<<1, 192, 0, stream>>>(partials, bn_gamma, bn_beta, scsh);
    k5_out<<<dim3(NTILES, BB), 256, 0, stream>>>(amax, amin, scsh, out);
}